// Round 1
// baseline (1615.084 us; speedup 1.0000x reference)
//
#include <hip/hip_runtime.h>
#include <math.h>

#define BB 2
#define LL 4096
#define DD 1024
#define NORD 2
#define NEMB 3
#define NFO 64
#define KW 3
#define TAPS 128   // window=exp(-0.5*n) -> e^-64 at n=128; exact truncation

__device__ __forceinline__ float gelu_exact(float x) {
    return 0.5f * x * (1.0f + erff(x * 0.70710678118654752440f));
}

// ---------------------------------------------------------------------------
// Implicit filter: h[i][n][c] for n in [0,TAPS). One block per (i,n).
// ---------------------------------------------------------------------------
__global__ __launch_bounds__(256) void filter_kernel(
    const float* __restrict__ freqs, const float* __restrict__ w1, const float* __restrict__ b1,
    const float* __restrict__ w2, const float* __restrict__ b2,
    const float* __restrict__ w3, const float* __restrict__ b3,
    const float* __restrict__ decay, float* __restrict__ hout)
{
    const int i = blockIdx.x / TAPS;
    const int n = blockIdx.x % TAPS;
    const int tid = threadIdx.x;
    const float t = (float)n / (float)(LL - 1);

    __shared__ float s1[NFO];
    __shared__ float s2[NFO];

    if (tid < NFO) {
        float enc[7];
        const float* fr = freqs + i * NEMB;
        const float c2pi = 6.28318530717958647692f;
        #pragma unroll
        for (int e = 0; e < 3; ++e) {
            float a = c2pi * fr[e] * t;
            enc[e]     = sinf(a);
            enc[e + 3] = cosf(a);
        }
        enc[6] = t;
        const float* w = w1 + i * 7 * NFO;
        float acc = b1[i * NFO + tid];
        #pragma unroll
        for (int e = 0; e < 7; ++e) acc += enc[e] * w[e * NFO + tid];
        s1[tid] = gelu_exact(acc);
    }
    __syncthreads();
    if (tid < NFO) {
        const float* w = w2 + i * NFO * NFO;
        float acc = b2[i * NFO + tid];
        #pragma unroll 8
        for (int g = 0; g < NFO; ++g) acc += s1[g] * w[g * NFO + tid];
        s2[tid] = gelu_exact(acc);
    }
    __syncthreads();

    const int c0 = tid * 4;          // 256 threads x 4 channels = 1024
    const float* w = w3 + (size_t)i * NFO * DD + c0;
    float4 acc = *(const float4*)(b3 + (size_t)i * DD + c0);
    #pragma unroll 8
    for (int g = 0; g < NFO; ++g) {
        float hg = s2[g];
        float4 wv = *(const float4*)(w + (size_t)g * DD);
        acc.x += hg * wv.x; acc.y += hg * wv.y; acc.z += hg * wv.z; acc.w += hg * wv.w;
    }
    float4 dc = *(const float4*)(decay + (size_t)i * DD + c0);
    float tl = t * (float)LL;
    acc.x *= expf(-fabsf(dc.x) * tl);
    acc.y *= expf(-fabsf(dc.y) * tl);
    acc.z *= expf(-fabsf(dc.z) * tl);
    acc.w *= expf(-fabsf(dc.w) * tl);
    *(float4*)(hout + ((size_t)i * TAPS + n) * DD + c0) = acc;
}

// ---------------------------------------------------------------------------
// Causal 128-tap per-channel conv: y[b,t,c] = sum_u h[u,c] * v[b,t-u,c]
// Tile: 64 t x 32 c per block; sliding register window (8 t per thread).
// ---------------------------------------------------------------------------
#define CTT 64
#define CCC 32
__global__ __launch_bounds__(256) void causal_conv_kernel(
    const float* __restrict__ v,      // (B,L,D) dense
    const float* __restrict__ hflt,   // (TAPS,D)
    float* __restrict__ y)            // (B,L,D) dense
{
    const int t0 = blockIdx.x * CTT;
    const int c0 = blockIdx.y * CCC;
    const int b  = blockIdx.z;
    const int tid = threadIdx.x;

    __shared__ float sv[CTT + TAPS - 1][CCC];   // rows t0-127 .. t0+63
    __shared__ float sh[TAPS][CCC];

    const float* vb = v + (size_t)b * LL * DD;
    for (int idx = tid; idx < (CTT + TAPS - 1) * CCC; idx += 256) {
        int r = idx / CCC, c = idx % CCC;
        int t = t0 - (TAPS - 1) + r;
        sv[r][c] = (t >= 0) ? vb[(size_t)t * DD + c0 + c] : 0.0f;
    }
    for (int idx = tid; idx < TAPS * CCC; idx += 256) {
        int u = idx / CCC, c = idx % CCC;
        sh[u][c] = hflt[(size_t)u * DD + c0 + c];
    }
    __syncthreads();

    const int tx = tid % CCC;     // channel
    const int ty = tid / CCC;     // 0..7 -> t-group of 8
    const int base = (TAPS - 1) + ty * 8;

    float acc[8];
    float win[8];
    #pragma unroll
    for (int j = 0; j < 8; ++j) { acc[j] = 0.0f; win[j] = sv[base + j][tx]; }

    for (int u = 0; u < TAPS; ++u) {
        float hu = sh[u][tx];
        #pragma unroll
        for (int j = 0; j < 8; ++j) acc[j] += hu * win[j];
        if (u < TAPS - 1) {
            #pragma unroll
            for (int j = 7; j > 0; --j) win[j] = win[j - 1];
            win[0] = sv[base - u - 1][tx];
        }
    }

    float* yb = y + ((size_t)b * LL + t0) * DD + c0;
    #pragma unroll
    for (int j = 0; j < 8; ++j) yb[(size_t)(ty * 8 + j) * DD + tx] = acc[j];
}

// ---------------------------------------------------------------------------
// Depthwise K=3 'same' conv + bias: xc[b,t,c] = sum_k w[k,c]*ctrl[b,t+k-1,c] + bias[c]
// ---------------------------------------------------------------------------
__global__ __launch_bounds__(256) void dwconv_kernel(
    const float* __restrict__ ctrl, const float* __restrict__ cw,
    const float* __restrict__ cb, float* __restrict__ xc)
{
    size_t idx = (size_t)blockIdx.x * 256 + threadIdx.x;  // float4 units
    int c4 = (int)(idx & 255) * 4;
    size_t bt = idx >> 8;             // 0 .. B*L-1
    int t = (int)(bt & (LL - 1));

    const float* base = ctrl + bt * DD + c4;
    float4 w0 = *(const float4*)(cw + 0 * DD + c4);
    float4 w1 = *(const float4*)(cw + 1 * DD + c4);
    float4 w2 = *(const float4*)(cw + 2 * DD + c4);
    float4 bs = *(const float4*)(cb + c4);

    float4 xm = make_float4(0.f, 0.f, 0.f, 0.f);
    float4 xp = make_float4(0.f, 0.f, 0.f, 0.f);
    if (t > 0)      xm = *(const float4*)(base - DD);
    float4 x0 = *(const float4*)(base);
    if (t < LL - 1) xp = *(const float4*)(base + DD);

    float4 o;
    o.x = w0.x * xm.x + w1.x * x0.x + w2.x * xp.x + bs.x;
    o.y = w0.y * xm.y + w1.y * x0.y + w2.y * xp.y + bs.y;
    o.z = w0.z * xm.z + w1.z * x0.z + w2.z * xp.z + bs.z;
    o.w = w0.w * xm.w + w1.w * x0.w + w2.w * xp.w + bs.w;
    *(float4*)(xc + bt * DD + c4) = o;
}

// ---------------------------------------------------------------------------
// f32 GEMM: C = A(MxK) @ W(KxN) + bias, tile 64x64, BK=16, 256 thr, 4x4/thread
// EPI 0: store.  EPI 1 (gate): out = vconv * A[r,c] * sigmoid(C + bias)
// ---------------------------------------------------------------------------
template <int EPI>
__global__ __launch_bounds__(256) void gemm64_kernel(
    const float* __restrict__ A, int lda,
    const float* __restrict__ W, int ldw,
    const float* __restrict__ bias,
    const float* __restrict__ vconv,
    float* __restrict__ Cout, int ldc,
    int K)
{
    __shared__ float As[16][64];
    __shared__ float Bs[16][64];

    const int bx = blockIdx.x;   // N/64
    const int by = blockIdx.y;   // M/64
    const int tid = threadIdx.x;
    const int tx = tid % 16;     // 0..15 -> 4 cols each
    const int ty = tid / 16;     // 0..15 -> 4 rows each

    const float* Ab = A + (size_t)(by * 64) * lda;
    const float* Wb = W + (size_t)(bx * 64);

    const int arow  = tid / 4;
    const int acol4 = (tid % 4) * 4;
    const int brow  = tid / 16;
    const int bcol4 = (tid % 16) * 4;

    float acc[4][4];
    #pragma unroll
    for (int i = 0; i < 4; ++i)
        #pragma unroll
        for (int j = 0; j < 4; ++j) acc[i][j] = 0.0f;

    for (int k0 = 0; k0 < K; k0 += 16) {
        float4 av = *(const float4*)(Ab + (size_t)arow * lda + k0 + acol4);
        float4 bv = *(const float4*)(Wb + (size_t)(k0 + brow) * ldw + bcol4);
        As[acol4 + 0][arow] = av.x;
        As[acol4 + 1][arow] = av.y;
        As[acol4 + 2][arow] = av.z;
        As[acol4 + 3][arow] = av.w;
        *(float4*)&Bs[brow][bcol4] = bv;
        __syncthreads();
        #pragma unroll
        for (int kk = 0; kk < 16; ++kk) {
            float4 a4 = *(const float4*)&As[kk][ty * 4];
            float4 b4 = *(const float4*)&Bs[kk][tx * 4];
            acc[0][0] += a4.x * b4.x; acc[0][1] += a4.x * b4.y; acc[0][2] += a4.x * b4.z; acc[0][3] += a4.x * b4.w;
            acc[1][0] += a4.y * b4.x; acc[1][1] += a4.y * b4.y; acc[1][2] += a4.y * b4.z; acc[1][3] += a4.y * b4.w;
            acc[2][0] += a4.z * b4.x; acc[2][1] += a4.z * b4.y; acc[2][2] += a4.z * b4.z; acc[2][3] += a4.z * b4.w;
            acc[3][0] += a4.w * b4.x; acc[3][1] += a4.w * b4.y; acc[3][2] += a4.w * b4.z; acc[3][3] += a4.w * b4.w;
        }
        __syncthreads();
    }

    const int row0 = by * 64 + ty * 4;
    const int col0 = bx * 64 + tx * 4;
    float4 bias4 = *(const float4*)(bias + col0);
    #pragma unroll
    for (int i = 0; i < 4; ++i) {
        int r = row0 + i;
        float4 c;
        c.x = acc[i][0] + bias4.x;
        c.y = acc[i][1] + bias4.y;
        c.z = acc[i][2] + bias4.z;
        c.w = acc[i][3] + bias4.w;
        if (EPI == 1) {
            float4 xcv = *(const float4*)(A + (size_t)r * lda + col0);
            float4 vc  = *(const float4*)(vconv + (size_t)r * ldc + col0);
            c.x = vc.x * xcv.x * (1.0f / (1.0f + expf(-c.x)));
            c.y = vc.y * xcv.y * (1.0f / (1.0f + expf(-c.y)));
            c.z = vc.z * xcv.z * (1.0f / (1.0f + expf(-c.z)));
            c.w = vc.w * xcv.w * (1.0f / (1.0f + expf(-c.w)));
        }
        *(float4*)(Cout + (size_t)r * ldc + col0) = c;
    }
}

// ---------------------------------------------------------------------------
extern "C" void kernel_launch(void* const* d_in, const int* in_sizes, int n_in,
                              void* d_out, int out_size, void* d_ws, size_t ws_size,
                              hipStream_t stream) {
    const float* x     = (const float*)d_in[0];
    const float* ipw   = (const float*)d_in[1];
    const float* ipb   = (const float*)d_in[2];
    const float* opw   = (const float*)d_in[3];
    const float* opb   = (const float*)d_in[4];
    const float* freqs = (const float*)d_in[5];
    const float* w1    = (const float*)d_in[6];
    const float* b1    = (const float*)d_in[7];
    const float* w2    = (const float*)d_in[8];
    const float* b2    = (const float*)d_in[9];
    const float* w3    = (const float*)d_in[10];
    const float* b3    = (const float*)d_in[11];
    const float* decay = (const float*)d_in[12];
    const float* cw    = (const float*)d_in[13];
    const float* cb    = (const float*)d_in[14];
    const float* gw    = (const float*)d_in[15];
    const float* gb    = (const float*)d_in[16];
    float* out = (float*)d_out;

    float* ws   = (float*)d_ws;
    float* h    = ws;                                    // NORD*TAPS*DD
    float* bufA = h    + (size_t)NORD * TAPS * DD;       // B*L*D each
    float* bufB = bufA + (size_t)BB * LL * DD;
    float* bufC = bufB + (size_t)BB * LL * DD;

    dim3 blk(256);
    dim3 ggemm(DD / 64, (BB * LL) / 64);
    dim3 gconv(LL / CTT, DD / CCC, BB);
    int  gdw = (BB * LL * DD / 4) / 256;

    // 1. implicit filters (both orders, first TAPS taps)
    filter_kernel<<<NORD * TAPS, blk, 0, stream>>>(freqs, w1, b1, w2, b2, w3, b3, decay, h);
    // 2. v0 = x @ ipw[:, 0:D] + b          -> bufA
    gemm64_kernel<0><<<ggemm, blk, 0, stream>>>(x, DD, ipw + 0 * DD, 3 * DD, ipb + 0 * DD, nullptr, bufA, DD, DD);
    // 3. vconv0 = causalconv(v0, h0)       -> bufB
    causal_conv_kernel<<<gconv, blk, 0, stream>>>(bufA, h, bufB);
    // 4. ctrl0 = x @ ipw[:, D:2D] + b      -> bufA
    gemm64_kernel<0><<<ggemm, blk, 0, stream>>>(x, DD, ipw + 1 * DD, 3 * DD, ipb + 1 * DD, nullptr, bufA, DD, DD);
    // 5. xc0 = dwconv(ctrl0)               -> bufC
    dwconv_kernel<<<gdw, blk, 0, stream>>>(bufA, cw, cb, bufC);
    // 6. v = vconv0 * xc0 * sigmoid(xc0 @ gw0 + gb0)   -> bufA
    gemm64_kernel<1><<<ggemm, blk, 0, stream>>>(bufC, DD, gw, DD, gb, bufB, bufA, DD, DD);
    // 7. ctrl1 = x @ ipw[:, 2D:3D] + b     -> bufB
    gemm64_kernel<0><<<ggemm, blk, 0, stream>>>(x, DD, ipw + 2 * DD, 3 * DD, ipb + 2 * DD, nullptr, bufB, DD, DD);
    // 8. xc1 = dwconv(ctrl1)               -> bufC
    dwconv_kernel<<<gdw, blk, 0, stream>>>(bufB, cw + (size_t)KW * DD, cb + DD, bufC);
    // 9. vconv1 = causalconv(v, h1)        -> bufB
    causal_conv_kernel<<<gconv, blk, 0, stream>>>(bufA, h + (size_t)TAPS * DD, bufB);
    // 10. v = vconv1 * xc1 * sigmoid(xc1 @ gw1 + gb1)  -> bufA
    gemm64_kernel<1><<<ggemm, blk, 0, stream>>>(bufC, DD, gw + (size_t)DD * DD, DD, gb + DD, bufB, bufA, DD, DD);
    // 11. out = v @ opw + opb              -> d_out
    gemm64_kernel<0><<<ggemm, blk, 0, stream>>>(bufA, DD, opw, DD, opb, nullptr, out, DD, DD);
}

// Round 2
// 409.009 us; speedup vs baseline: 3.9488x; 3.9488x over previous
//
#include <hip/hip_runtime.h>
#include <math.h>

#define BB 2
#define LL 4096
#define DD 1024
#define NORD 2
#define NEMB 3
#define NFO 64
#define KW 3
#define TAPS 128   // window=exp(-0.5*n) -> e^-64 at n=128; exact truncation

typedef __attribute__((ext_vector_type(8))) short bf16x8;
typedef __attribute__((ext_vector_type(4))) float f32x4;

__device__ __forceinline__ void gl_lds16(const void* g, void* s) {
    __builtin_amdgcn_global_load_lds(
        (const __attribute__((address_space(1))) void*)g,
        (__attribute__((address_space(3))) void*)s, 16, 0, 0);
}

__device__ __forceinline__ float bf2f(unsigned short u) {
    union { unsigned int i; float f; } v; v.i = ((unsigned int)u) << 16; return v.f;
}
__device__ __forceinline__ unsigned short f2bf(float f) {
    union { float f; unsigned int i; } v; v.f = f;
    unsigned int r = v.i + 0x7FFF + ((v.i >> 16) & 1);   // round-nearest-even
    return (unsigned short)(r >> 16);
}

__device__ __forceinline__ float gelu_exact(float x) {
    return 0.5f * x * (1.0f + erff(x * 0.70710678118654752440f));
}

// ---------------------------------------------------------------------------
// f32 -> bf16 bulk convert (8 elems / thread)
// ---------------------------------------------------------------------------
__global__ __launch_bounds__(256) void cvt_bf16_kernel(
    const float* __restrict__ src, unsigned short* __restrict__ dst)
{
    size_t i = ((size_t)blockIdx.x * 256 + threadIdx.x) * 8;
    float4 a = *(const float4*)(src + i);
    float4 b = *(const float4*)(src + i + 4);
    bf16x8 o;
    o[0] = (short)f2bf(a.x); o[1] = (short)f2bf(a.y); o[2] = (short)f2bf(a.z); o[3] = (short)f2bf(a.w);
    o[4] = (short)f2bf(b.x); o[5] = (short)f2bf(b.y); o[6] = (short)f2bf(b.z); o[7] = (short)f2bf(b.w);
    *(bf16x8*)(dst + i) = o;
}

// ---------------------------------------------------------------------------
// Weight transpose+convert: src (K x N f32, row-major) -> dst (N x K bf16)
// ---------------------------------------------------------------------------
__global__ __launch_bounds__(256) void wtrans_kernel(
    const float* __restrict__ src, unsigned short* __restrict__ dst, int K, int N)
{
    __shared__ float t[32][33];
    const int n0 = blockIdx.x * 32;
    const int k0 = blockIdx.y * 32;
    const int tid = threadIdx.x;
    const int r = tid >> 5;       // 0..7
    const int c = tid & 31;
    #pragma unroll
    for (int p = 0; p < 4; ++p)
        t[r + p * 8][c] = src[(size_t)(k0 + r + p * 8) * N + n0 + c];
    __syncthreads();
    #pragma unroll
    for (int p = 0; p < 4; ++p)
        dst[(size_t)(n0 + r + p * 8) * K + k0 + c] = f2bf(t[c][r + p * 8]);
}

// ---------------------------------------------------------------------------
// Implicit filter: h[i][n][c] for n in [0,TAPS). One block per (i,n).
// ---------------------------------------------------------------------------
__global__ __launch_bounds__(256) void filter_kernel(
    const float* __restrict__ freqs, const float* __restrict__ w1, const float* __restrict__ b1,
    const float* __restrict__ w2, const float* __restrict__ b2,
    const float* __restrict__ w3, const float* __restrict__ b3,
    const float* __restrict__ decay, float* __restrict__ hout)
{
    const int i = blockIdx.x / TAPS;
    const int n = blockIdx.x % TAPS;
    const int tid = threadIdx.x;
    const float t = (float)n / (float)(LL - 1);

    __shared__ float s1[NFO];
    __shared__ float s2[NFO];

    if (tid < NFO) {
        float enc[7];
        const float* fr = freqs + i * NEMB;
        const float c2pi = 6.28318530717958647692f;
        #pragma unroll
        for (int e = 0; e < 3; ++e) {
            float a = c2pi * fr[e] * t;
            enc[e]     = sinf(a);
            enc[e + 3] = cosf(a);
        }
        enc[6] = t;
        const float* w = w1 + i * 7 * NFO;
        float acc = b1[i * NFO + tid];
        #pragma unroll
        for (int e = 0; e < 7; ++e) acc += enc[e] * w[e * NFO + tid];
        s1[tid] = gelu_exact(acc);
    }
    __syncthreads();
    if (tid < NFO) {
        const float* w = w2 + i * NFO * NFO;
        float acc = b2[i * NFO + tid];
        #pragma unroll 8
        for (int g = 0; g < NFO; ++g) acc += s1[g] * w[g * NFO + tid];
        s2[tid] = gelu_exact(acc);
    }
    __syncthreads();

    const int c0 = tid * 4;
    const float* w = w3 + (size_t)i * NFO * DD + c0;
    float4 acc = *(const float4*)(b3 + (size_t)i * DD + c0);
    #pragma unroll 8
    for (int g = 0; g < NFO; ++g) {
        float hg = s2[g];
        float4 wv = *(const float4*)(w + (size_t)g * DD);
        acc.x += hg * wv.x; acc.y += hg * wv.y; acc.z += hg * wv.z; acc.w += hg * wv.w;
    }
    float4 dc = *(const float4*)(decay + (size_t)i * DD + c0);
    float tl = t * (float)LL;
    acc.x *= expf(-fabsf(dc.x) * tl);
    acc.y *= expf(-fabsf(dc.y) * tl);
    acc.z *= expf(-fabsf(dc.z) * tl);
    acc.w *= expf(-fabsf(dc.w) * tl);
    *(float4*)(hout + ((size_t)i * TAPS + n) * DD + c0) = acc;
}

// ---------------------------------------------------------------------------
// Causal 128-tap per-channel conv (f32 in, f32 out)
// ---------------------------------------------------------------------------
#define CTT 64
#define CCC 32
__global__ __launch_bounds__(256) void causal_conv_kernel(
    const float* __restrict__ v, const float* __restrict__ hflt, float* __restrict__ y)
{
    const int t0 = blockIdx.x * CTT;
    const int c0 = blockIdx.y * CCC;
    const int b  = blockIdx.z;
    const int tid = threadIdx.x;

    __shared__ float sv[CTT + TAPS - 1][CCC];
    __shared__ float sh[TAPS][CCC];

    const float* vb = v + (size_t)b * LL * DD;
    for (int idx = tid; idx < (CTT + TAPS - 1) * CCC; idx += 256) {
        int r = idx / CCC, c = idx % CCC;
        int t = t0 - (TAPS - 1) + r;
        sv[r][c] = (t >= 0) ? vb[(size_t)t * DD + c0 + c] : 0.0f;
    }
    for (int idx = tid; idx < TAPS * CCC; idx += 256) {
        int u = idx / CCC, c = idx % CCC;
        sh[u][c] = hflt[(size_t)u * DD + c0 + c];
    }
    __syncthreads();

    const int tx = tid % CCC;
    const int ty = tid / CCC;
    const int base = (TAPS - 1) + ty * 8;

    float acc[8];
    float win[8];
    #pragma unroll
    for (int j = 0; j < 8; ++j) { acc[j] = 0.0f; win[j] = sv[base + j][tx]; }

    for (int u = 0; u < TAPS; ++u) {
        float hu = sh[u][tx];
        #pragma unroll
        for (int j = 0; j < 8; ++j) acc[j] += hu * win[j];
        if (u < TAPS - 1) {
            #pragma unroll
            for (int j = 7; j > 0; --j) win[j] = win[j - 1];
            win[0] = sv[base - u - 1][tx];
        }
    }

    float* yb = y + ((size_t)b * LL + t0) * DD + c0;
    #pragma unroll
    for (int j = 0; j < 8; ++j) yb[(size_t)(ty * 8 + j) * DD + tx] = acc[j];
}

// ---------------------------------------------------------------------------
// Depthwise K=3 conv, bf16 in -> bf16 out. ctrl has leading dim `ld`.
// ---------------------------------------------------------------------------
__global__ __launch_bounds__(256) void dwconv_bf16_kernel(
    const unsigned short* __restrict__ ctrl, int ld,
    const float* __restrict__ cw, const float* __restrict__ cb,
    unsigned short* __restrict__ xc)
{
    size_t idx = (size_t)blockIdx.x * 256 + threadIdx.x;  // 8-channel units
    int c8 = (int)(idx & 127) * 8;
    size_t bt = idx >> 7;
    int t = (int)(bt & (LL - 1));

    const unsigned short* base = ctrl + bt * ld + c8;
    bf16x8 xm = {}, xp = {};
    bf16x8 x0 = *(const bf16x8*)(base);
    if (t > 0)      xm = *(const bf16x8*)(base - ld);
    if (t < LL - 1) xp = *(const bf16x8*)(base + ld);

    bf16x8 o;
    #pragma unroll
    for (int q = 0; q < 8; ++q) {
        int c = c8 + q;
        float r = cw[0 * DD + c] * bf2f((unsigned short)xm[q])
                + cw[1 * DD + c] * bf2f((unsigned short)x0[q])
                + cw[2 * DD + c] * bf2f((unsigned short)xp[q])
                + cb[c];
        o[q] = (short)f2bf(r);
    }
    *(bf16x8*)(xc + bt * DD + c8) = o;
}

// ---------------------------------------------------------------------------
// bf16 MFMA GEMM (m97 structure): C = A(MxK) @ BT(NxK)^T + bias
// 128x128 tile, BK=32, 4 waves (2x2 of 64x64), global_load_lds staging,
// XOR slot-swizzle (pre-swizzled source + swizzled ds_read).
// EPI 0: f32 store   1: bf16 store
// EPI 2: f32  v = vconv * xc * sigmoid(acc+bias)   3: same, bf16 store
// (EPI 2/3 require N == K so A[row][col] is the xc operand)
// ---------------------------------------------------------------------------
template <int EPI>
__global__ __launch_bounds__(256) void gemm_bf16_kernel(
    const unsigned short* __restrict__ A,    // M x K, lda = K
    const unsigned short* __restrict__ BT,   // N x K, ldb = K
    const float* __restrict__ bias,          // N
    const float* __restrict__ vconv,         // M x N f32 (EPI 2/3)
    void* __restrict__ Cout,
    int Nblk, int Kdim, int ldc)
{
    __shared__ short As[128 * 32];
    __shared__ short Bs[128 * 32];

    const int tid  = threadIdx.x;
    const int wave = tid >> 6;
    const int lane = tid & 63;

    // bijective XCD swizzle (nwg % 8 == 0 for all launches)
    const int nwg  = gridDim.x;
    const int orig = blockIdx.x;
    const int wg   = (orig & 7) * (nwg >> 3) + (orig >> 3);
    const int by   = wg / Nblk;
    const int bx   = wg % Nblk;

    const int wm  = (wave >> 1) * 64;
    const int wn  = (wave & 1) * 64;
    const int llo = lane & 15;
    const int lhi = lane >> 4;

    // ---- staging addresses (pre-swizzled global source) ----
    const int sr0   = tid >> 2;                 // tile row (call 0); call 1 adds 64
    const int sslot = tid & 3;                  // 16B slot within 64B row
    const int ssrc  = sslot ^ ((sr0 >> 1) & 3); // same g for row and row+64
    const unsigned short* Ag0 = A  + (size_t)(by * 128 + sr0) * Kdim + ssrc * 8;
    const unsigned short* Ag1 = Ag0 + (size_t)64 * Kdim;
    const unsigned short* Bg0 = BT + (size_t)(bx * 128 + sr0) * Kdim + ssrc * 8;
    const unsigned short* Bg1 = Bg0 + (size_t)64 * Kdim;
    char* AsB = (char*)As;
    char* BsB = (char*)Bs;
    const int l0 = wave * 1024;                 // wave-uniform LDS byte base

    // ---- ds_read addresses (swizzled) ----
    const int sA = lhi ^ ((llo >> 1) & 3);
    const short* ArdBase = As + (wm + llo) * 32 + sA * 8;
    const short* BrdBase = Bs + (wn + llo) * 32 + sA * 8;

    f32x4 acc[4][4] = {};

    for (int k0 = 0; k0 < Kdim; k0 += 32) {
        gl_lds16(Ag0 + k0, AsB + l0);
        gl_lds16(Ag1 + k0, AsB + 4096 + l0);
        gl_lds16(Bg0 + k0, BsB + l0);
        gl_lds16(Bg1 + k0, BsB + 4096 + l0);
        __syncthreads();

        bf16x8 af[4], bf[4];
        #pragma unroll
        for (int i = 0; i < 4; ++i) {
            af[i] = *(const bf16x8*)(ArdBase + i * 512);
            bf[i] = *(const bf16x8*)(BrdBase + i * 512);
        }
        #pragma unroll
        for (int i = 0; i < 4; ++i)
            #pragma unroll
            for (int j = 0; j < 4; ++j)
                acc[i][j] = __builtin_amdgcn_mfma_f32_16x16x32_bf16(af[i], bf[j], acc[i][j], 0, 0, 0);
        __syncthreads();
    }

    // ---- epilogue: C/D layout col=lane&15, row=(lane>>4)*4+reg ----
    const int row0 = by * 128 + wm + lhi * 4;
    const int col0 = bx * 128 + wn + llo;
    #pragma unroll
    for (int j = 0; j < 4; ++j) {
        const int col = col0 + j * 16;
        const float bj = bias[col];
        #pragma unroll
        for (int i = 0; i < 4; ++i) {
            #pragma unroll
            for (int r = 0; r < 4; ++r) {
                const int rowg = row0 + i * 16 + r;
                float v = acc[i][j][r] + bj;
                if (EPI == 0) {
                    ((float*)Cout)[(size_t)rowg * ldc + col] = v;
                } else if (EPI == 1) {
                    ((unsigned short*)Cout)[(size_t)rowg * ldc + col] = f2bf(v);
                } else {
                    float xc = bf2f(A[(size_t)rowg * Kdim + col]);
                    float vc = vconv[(size_t)rowg * 1024 + col];
                    float o  = vc * xc * (1.0f / (1.0f + expf(-v)));
                    if (EPI == 2) ((float*)Cout)[(size_t)rowg * ldc + col] = o;
                    else          ((unsigned short*)Cout)[(size_t)rowg * ldc + col] = f2bf(o);
                }
            }
        }
    }
}

// ---------------------------------------------------------------------------
extern "C" void kernel_launch(void* const* d_in, const int* in_sizes, int n_in,
                              void* d_out, int out_size, void* d_ws, size_t ws_size,
                              hipStream_t stream) {
    const float* x     = (const float*)d_in[0];
    const float* ipw   = (const float*)d_in[1];
    const float* ipb   = (const float*)d_in[2];
    const float* opw   = (const float*)d_in[3];
    const float* opb   = (const float*)d_in[4];
    const float* freqs = (const float*)d_in[5];
    const float* w1    = (const float*)d_in[6];
    const float* b1    = (const float*)d_in[7];
    const float* w2    = (const float*)d_in[8];
    const float* b2    = (const float*)d_in[9];
    const float* w3    = (const float*)d_in[10];
    const float* b3    = (const float*)d_in[11];
    const float* decay = (const float*)d_in[12];
    const float* cw    = (const float*)d_in[13];
    const float* cb    = (const float*)d_in[14];
    const float* gw    = (const float*)d_in[15];
    const float* gb    = (const float*)d_in[16];
    float* out = (float*)d_out;

    // workspace layout (114.3 MB)
    char* w = (char*)d_ws;
    float* h             = (float*)w;                                // 2*128*1024 f32
    unsigned short* ipwT = (unsigned short*)(w + (size_t)1048576);   // 3072x1024 bf16
    unsigned short* gw0T = ipwT + (size_t)3072 * 1024;               // 1024x1024
    unsigned short* gw1T = gw0T + (size_t)1024 * 1024;
    unsigned short* opwT = gw1T + (size_t)1024 * 1024;
    unsigned short* xb   = opwT + (size_t)1024 * 1024;               // 8192x1024 bf16 (x, later v2)
    float* V             = (float*)(xb + (size_t)8192 * 1024);       // 8192x1024 f32 (v0, v1)
    unsigned short* ctrlB= (unsigned short*)(V + (size_t)8192 * 1024); // 8192x2048 bf16
    unsigned short* xcB  = ctrlB + (size_t)8192 * 2048;              // 8192x1024 bf16
    float* vconv         = out;                                      // d_out as f32 scratch

    dim3 blk(256);
    dim3 gconv(LL / CTT, DD / CCC, BB);

    // conversions
    cvt_bf16_kernel<<<4096, blk, 0, stream>>>(x, xb);
    wtrans_kernel<<<dim3(96, 32), blk, 0, stream>>>(ipw, ipwT, 1024, 3072);
    wtrans_kernel<<<dim3(32, 32), blk, 0, stream>>>(gw, gw0T, 1024, 1024);
    wtrans_kernel<<<dim3(32, 32), blk, 0, stream>>>(gw + (size_t)1024 * 1024, gw1T, 1024, 1024);
    wtrans_kernel<<<dim3(32, 32), blk, 0, stream>>>(opw, opwT, 1024, 1024);

    // implicit filters
    filter_kernel<<<NORD * TAPS, blk, 0, stream>>>(freqs, w1, b1, w2, b2, w3, b3, decay, h);

    // v0 = x @ ipw[:, :1024] + b  (f32 -> V)
    gemm_bf16_kernel<0><<<512, blk, 0, stream>>>(xb, ipwT, ipb, nullptr, V, 8, 1024, 1024);
    // ctrl = x @ ipw[:, 1024:] + b  (bf16 -> ctrlB)
    gemm_bf16_kernel<1><<<1024, blk, 0, stream>>>(xb, ipwT + (size_t)1024 * 1024, ipb + 1024, nullptr, ctrlB, 16, 1024, 2048);

    // order 0
    causal_conv_kernel<<<gconv, blk, 0, stream>>>(V, h, vconv);
    dwconv_bf16_kernel<<<4096, blk, 0, stream>>>(ctrlB, 2048, cw, cb, xcB);
    gemm_bf16_kernel<2><<<512, blk, 0, stream>>>(xcB, gw0T, gb, vconv, V, 8, 1024, 1024);

    // order 1
    causal_conv_kernel<<<gconv, blk, 0, stream>>>(V, h + (size_t)TAPS * DD, vconv);
    dwconv_bf16_kernel<<<4096, blk, 0, stream>>>(ctrlB + 1024, 2048, cw + (size_t)KW * DD, cb + DD, xcB);
    gemm_bf16_kernel<3><<<512, blk, 0, stream>>>(xcB, gw1T, gb + DD, vconv, xb, 8, 1024, 1024);

    // out = v2 @ opw + opb
    gemm_bf16_kernel<0><<<512, blk, 0, stream>>>(xb, opwT, opb, nullptr, out, 8, 1024, 1024);
}

// Round 3
// 310.789 us; speedup vs baseline: 5.1967x; 1.3160x over previous
//
#include <hip/hip_runtime.h>
#include <math.h>

#define BB 2
#define LL 4096
#define DD 1024
#define NORD 2
#define NEMB 3
#define NFO 64
#define KW 3
#define TAPS 64    // window=exp(-0.5*n) -> e^-32 at n=64; exact truncation in f32

typedef __attribute__((ext_vector_type(8))) short bf16x8;
typedef __attribute__((ext_vector_type(4))) float f32x4;

__device__ __forceinline__ void gl_lds16(const void* g, void* s) {
    __builtin_amdgcn_global_load_lds(
        (const __attribute__((address_space(1))) void*)g,
        (__attribute__((address_space(3))) void*)s, 16, 0, 0);
}

__device__ __forceinline__ float bf2f(unsigned short u) {
    union { unsigned int i; float f; } v; v.i = ((unsigned int)u) << 16; return v.f;
}
__device__ __forceinline__ unsigned short f2bf(float f) {
    union { float f; unsigned int i; } v; v.f = f;
    unsigned int r = v.i + 0x7FFF + ((v.i >> 16) & 1);   // round-nearest-even
    return (unsigned short)(r >> 16);
}

__device__ __forceinline__ float gelu_exact(float x) {
    return 0.5f * x * (1.0f + erff(x * 0.70710678118654752440f));
}

// ---------------------------------------------------------------------------
// f32 -> bf16 bulk convert (8 elems / thread)
// ---------------------------------------------------------------------------
__global__ __launch_bounds__(256) void cvt_bf16_kernel(
    const float* __restrict__ src, unsigned short* __restrict__ dst)
{
    size_t i = ((size_t)blockIdx.x * 256 + threadIdx.x) * 8;
    float4 a = *(const float4*)(src + i);
    float4 b = *(const float4*)(src + i + 4);
    bf16x8 o;
    o[0] = (short)f2bf(a.x); o[1] = (short)f2bf(a.y); o[2] = (short)f2bf(a.z); o[3] = (short)f2bf(a.w);
    o[4] = (short)f2bf(b.x); o[5] = (short)f2bf(b.y); o[6] = (short)f2bf(b.z); o[7] = (short)f2bf(b.w);
    *(bf16x8*)(dst + i) = o;
}

// ---------------------------------------------------------------------------
// Weight transpose+convert: src (K x N f32, row-major) -> dst (N x K bf16)
// ---------------------------------------------------------------------------
__global__ __launch_bounds__(256) void wtrans_kernel(
    const float* __restrict__ src, unsigned short* __restrict__ dst, int K, int N)
{
    __shared__ float t[32][33];
    const int n0 = blockIdx.x * 32;
    const int k0 = blockIdx.y * 32;
    const int tid = threadIdx.x;
    const int r = tid >> 5;       // 0..7
    const int c = tid & 31;
    #pragma unroll
    for (int p = 0; p < 4; ++p)
        t[r + p * 8][c] = src[(size_t)(k0 + r + p * 8) * N + n0 + c];
    __syncthreads();
    #pragma unroll
    for (int p = 0; p < 4; ++p)
        dst[(size_t)(n0 + r + p * 8) * K + k0 + c] = f2bf(t[c][r + p * 8]);
}

// ---------------------------------------------------------------------------
// Implicit filter: h[i][n][c] for n in [0,TAPS). One block per (i,n).
// ---------------------------------------------------------------------------
__global__ __launch_bounds__(256) void filter_kernel(
    const float* __restrict__ freqs, const float* __restrict__ w1, const float* __restrict__ b1,
    const float* __restrict__ w2, const float* __restrict__ b2,
    const float* __restrict__ w3, const float* __restrict__ b3,
    const float* __restrict__ decay, float* __restrict__ hout)
{
    const int i = blockIdx.x / TAPS;
    const int n = blockIdx.x % TAPS;
    const int tid = threadIdx.x;
    const float t = (float)n / (float)(LL - 1);

    __shared__ float s1[NFO];
    __shared__ float s2[NFO];

    if (tid < NFO) {
        float enc[7];
        const float* fr = freqs + i * NEMB;
        const float c2pi = 6.28318530717958647692f;
        #pragma unroll
        for (int e = 0; e < 3; ++e) {
            float a = c2pi * fr[e] * t;
            enc[e]     = sinf(a);
            enc[e + 3] = cosf(a);
        }
        enc[6] = t;
        const float* w = w1 + i * 7 * NFO;
        float acc = b1[i * NFO + tid];
        #pragma unroll
        for (int e = 0; e < 7; ++e) acc += enc[e] * w[e * NFO + tid];
        s1[tid] = gelu_exact(acc);
    }
    __syncthreads();
    if (tid < NFO) {
        const float* w = w2 + i * NFO * NFO;
        float acc = b2[i * NFO + tid];
        #pragma unroll 8
        for (int g = 0; g < NFO; ++g) acc += s1[g] * w[g * NFO + tid];
        s2[tid] = gelu_exact(acc);
    }
    __syncthreads();

    const int c0 = tid * 4;
    const float* w = w3 + (size_t)i * NFO * DD + c0;
    float4 acc = *(const float4*)(b3 + (size_t)i * DD + c0);
    #pragma unroll 8
    for (int g = 0; g < NFO; ++g) {
        float hg = s2[g];
        float4 wv = *(const float4*)(w + (size_t)g * DD);
        acc.x += hg * wv.x; acc.y += hg * wv.y; acc.z += hg * wv.z; acc.w += hg * wv.w;
    }
    float4 dc = *(const float4*)(decay + (size_t)i * DD + c0);
    float tl = t * (float)LL;
    acc.x *= expf(-fabsf(dc.x) * tl);
    acc.y *= expf(-fabsf(dc.y) * tl);
    acc.z *= expf(-fabsf(dc.z) * tl);
    acc.w *= expf(-fabsf(dc.w) * tl);
    *(float4*)(hout + ((size_t)i * TAPS + n) * DD + c0) = acc;
}

// ---------------------------------------------------------------------------
// Causal 64-tap per-channel conv (f32 in, f32 out), move-free inner loop.
// Tile: 64 t x 32 c. Each thread: 8 outputs, 8 tap-chunks with static window.
// ---------------------------------------------------------------------------
#define CTT 64
#define CCC 32
__global__ __launch_bounds__(256) void causal_conv_kernel(
    const float* __restrict__ v, const float* __restrict__ hflt, float* __restrict__ y)
{
    const int t0 = blockIdx.x * CTT;
    const int c0 = blockIdx.y * CCC;
    const int b  = blockIdx.z;
    const int tid = threadIdx.x;

    __shared__ float sv[128][CCC];    // rows: t0-64 .. t0+63
    __shared__ float sh[TAPS][CCC];

    const float* vb = v + (size_t)b * LL * DD;
    #pragma unroll
    for (int q = 0; q < 4; ++q) {
        int idx = tid + q * 256;      // float4 units, 128*8 = 1024 total
        int row = idx >> 3;
        int c4  = (idx & 7) * 4;
        int t = t0 - 64 + row;
        float4 val = make_float4(0.f, 0.f, 0.f, 0.f);
        if (t >= 0) val = *(const float4*)(vb + (size_t)t * DD + c0 + c4);
        *(float4*)(&sv[row][c4]) = val;
    }
    #pragma unroll
    for (int q = 0; q < 2; ++q) {
        int idx = tid + q * 256;      // 64*8 = 512 float4 units
        int u   = idx >> 3;
        int c4  = (idx & 7) * 4;
        *(float4*)(&sh[u][c4]) = *(const float4*)(hflt + (size_t)u * DD + c0 + c4);
    }
    __syncthreads();

    const int tx = tid & 31;          // channel
    const int ty = tid >> 5;          // 0..7
    const int R0 = 64 + ty * 8;

    float acc[8] = {};
    #pragma unroll
    for (int m = 0; m < 8; ++m) {
        float W[15];
        #pragma unroll
        for (int p = 0; p < 15; ++p) W[p] = sv[R0 - 8 * m - 7 + p][tx];
        float h8[8];
        #pragma unroll
        for (int du = 0; du < 8; ++du) h8[du] = sh[8 * m + du][tx];
        #pragma unroll
        for (int du = 0; du < 8; ++du)
            #pragma unroll
            for (int j = 0; j < 8; ++j)
                acc[j] += h8[du] * W[7 + j - du];
    }

    float* yb = y + ((size_t)b * LL + t0) * DD + c0;
    #pragma unroll
    for (int j = 0; j < 8; ++j) yb[(size_t)(ty * 8 + j) * DD + tx] = acc[j];
}

// ---------------------------------------------------------------------------
// Depthwise K=3 conv, bf16 in -> bf16 out. ctrl has leading dim `ld`.
// ---------------------------------------------------------------------------
__global__ __launch_bounds__(256) void dwconv_bf16_kernel(
    const unsigned short* __restrict__ ctrl, int ld,
    const float* __restrict__ cw, const float* __restrict__ cb,
    unsigned short* __restrict__ xc)
{
    size_t idx = (size_t)blockIdx.x * 256 + threadIdx.x;  // 8-channel units
    int c8 = (int)(idx & 127) * 8;
    size_t bt = idx >> 7;
    int t = (int)(bt & (LL - 1));

    const unsigned short* base = ctrl + bt * ld + c8;
    bf16x8 xm = {}, xp = {};
    bf16x8 x0 = *(const bf16x8*)(base);
    if (t > 0)      xm = *(const bf16x8*)(base - ld);
    if (t < LL - 1) xp = *(const bf16x8*)(base + ld);

    bf16x8 o;
    #pragma unroll
    for (int q = 0; q < 8; ++q) {
        int c = c8 + q;
        float r = cw[0 * DD + c] * bf2f((unsigned short)xm[q])
                + cw[1 * DD + c] * bf2f((unsigned short)x0[q])
                + cw[2 * DD + c] * bf2f((unsigned short)xp[q])
                + cb[c];
        o[q] = (short)f2bf(r);
    }
    *(bf16x8*)(xc + bt * DD + c8) = o;
}

// ---------------------------------------------------------------------------
// bf16 MFMA GEMM (m97 structure): C = A(MxK) @ BT(NxK)^T + bias
// 128x128 tile, BK=32, 4 waves (2x2 of 64x64), global_load_lds staging,
// XOR slot-swizzle (pre-swizzled source + swizzled ds_read).
// EPI 0: f32 store   1: bf16 store
// EPI 2: f32  v = vconv * xc * sigmoid(acc+bias)   3: same, bf16 store
// EPI 4: split store: col<1024 -> f32 Cout (ldc 1024); else bf16 Cout2 (ldc 2048)
// ---------------------------------------------------------------------------
template <int EPI>
__global__ __launch_bounds__(256) void gemm_bf16_kernel(
    const unsigned short* __restrict__ A,    // M x K, lda = K
    const unsigned short* __restrict__ BT,   // N x K, ldb = K
    const float* __restrict__ bias,          // N
    const float* __restrict__ vconv,         // M x N f32 (EPI 2/3)
    void* __restrict__ Cout,
    int Nblk, int Kdim, int ldc,
    void* __restrict__ Cout2)
{
    __shared__ short As[128 * 32];
    __shared__ short Bs[128 * 32];

    const int tid  = threadIdx.x;
    const int wave = tid >> 6;
    const int lane = tid & 63;

    // bijective XCD swizzle (nwg % 8 == 0 for all launches)
    const int nwg  = gridDim.x;
    const int orig = blockIdx.x;
    const int wg   = (orig & 7) * (nwg >> 3) + (orig >> 3);
    const int by   = wg / Nblk;
    const int bx   = wg % Nblk;

    const int wm  = (wave >> 1) * 64;
    const int wn  = (wave & 1) * 64;
    const int llo = lane & 15;
    const int lhi = lane >> 4;

    // ---- staging addresses (pre-swizzled global source) ----
    const int sr0   = tid >> 2;                 // tile row (call 0); call 1 adds 64
    const int sslot = tid & 3;                  // 16B slot within 64B row
    const int ssrc  = sslot ^ ((sr0 >> 1) & 3); // same across row and row+64
    const unsigned short* Ag0 = A  + (size_t)(by * 128 + sr0) * Kdim + ssrc * 8;
    const unsigned short* Ag1 = Ag0 + (size_t)64 * Kdim;
    const unsigned short* Bg0 = BT + (size_t)(bx * 128 + sr0) * Kdim + ssrc * 8;
    const unsigned short* Bg1 = Bg0 + (size_t)64 * Kdim;
    char* AsB = (char*)As;
    char* BsB = (char*)Bs;
    const int l0 = wave * 1024;                 // wave-uniform LDS byte base

    // ---- ds_read addresses (swizzled) ----
    const int sA = lhi ^ ((llo >> 1) & 3);
    const short* ArdBase = As + (wm + llo) * 32 + sA * 8;
    const short* BrdBase = Bs + (wn + llo) * 32 + sA * 8;

    f32x4 acc[4][4] = {};

    for (int k0 = 0; k0 < Kdim; k0 += 32) {
        gl_lds16(Ag0 + k0, AsB + l0);
        gl_lds16(Ag1 + k0, AsB + 4096 + l0);
        gl_lds16(Bg0 + k0, BsB + l0);
        gl_lds16(Bg1 + k0, BsB + 4096 + l0);
        __syncthreads();

        bf16x8 af[4], bf[4];
        #pragma unroll
        for (int i = 0; i < 4; ++i) {
            af[i] = *(const bf16x8*)(ArdBase + i * 512);
            bf[i] = *(const bf16x8*)(BrdBase + i * 512);
        }
        #pragma unroll
        for (int i = 0; i < 4; ++i)
            #pragma unroll
            for (int j = 0; j < 4; ++j)
                acc[i][j] = __builtin_amdgcn_mfma_f32_16x16x32_bf16(af[i], bf[j], acc[i][j], 0, 0, 0);
        __syncthreads();
    }

    // ---- epilogue: C/D layout col=lane&15, row=(lane>>4)*4+reg ----
    const int row0 = by * 128 + wm + lhi * 4;
    const int col0 = bx * 128 + wn + llo;
    #pragma unroll
    for (int j = 0; j < 4; ++j) {
        const int col = col0 + j * 16;
        const float bj = bias[col];
        #pragma unroll
        for (int i = 0; i < 4; ++i) {
            #pragma unroll
            for (int r = 0; r < 4; ++r) {
                const int rowg = row0 + i * 16 + r;
                float v = acc[i][j][r] + bj;
                if (EPI == 0) {
                    ((float*)Cout)[(size_t)rowg * ldc + col] = v;
                } else if (EPI == 1) {
                    ((unsigned short*)Cout)[(size_t)rowg * ldc + col] = f2bf(v);
                } else if (EPI == 4) {
                    if (col < 1024) ((float*)Cout)[(size_t)rowg * 1024 + col] = v;
                    else ((unsigned short*)Cout2)[(size_t)rowg * 2048 + (col - 1024)] = f2bf(v);
                } else {
                    float xc = bf2f(A[(size_t)rowg * Kdim + col]);
                    float vc = vconv[(size_t)rowg * 1024 + col];
                    float o  = vc * xc * (1.0f / (1.0f + expf(-v)));
                    if (EPI == 2) ((float*)Cout)[(size_t)rowg * ldc + col] = o;
                    else          ((unsigned short*)Cout)[(size_t)rowg * ldc + col] = f2bf(o);
                }
            }
        }
    }
}

// ---------------------------------------------------------------------------
extern "C" void kernel_launch(void* const* d_in, const int* in_sizes, int n_in,
                              void* d_out, int out_size, void* d_ws, size_t ws_size,
                              hipStream_t stream) {
    const float* x     = (const float*)d_in[0];
    const float* ipw   = (const float*)d_in[1];
    const float* ipb   = (const float*)d_in[2];
    const float* opw   = (const float*)d_in[3];
    const float* opb   = (const float*)d_in[4];
    const float* freqs = (const float*)d_in[5];
    const float* w1    = (const float*)d_in[6];
    const float* b1    = (const float*)d_in[7];
    const float* w2    = (const float*)d_in[8];
    const float* b2    = (const float*)d_in[9];
    const float* w3    = (const float*)d_in[10];
    const float* b3    = (const float*)d_in[11];
    const float* decay = (const float*)d_in[12];
    const float* cw    = (const float*)d_in[13];
    const float* cb    = (const float*)d_in[14];
    const float* gw    = (const float*)d_in[15];
    const float* gb    = (const float*)d_in[16];
    float* out = (float*)d_out;

    // workspace layout
    char* w = (char*)d_ws;
    float* h             = (float*)w;                                // NORD*TAPS*DD f32
    unsigned short* ipwT = (unsigned short*)(w + (size_t)1048576);   // 3072x1024 bf16
    unsigned short* gw0T = ipwT + (size_t)3072 * 1024;               // 1024x1024
    unsigned short* gw1T = gw0T + (size_t)1024 * 1024;
    unsigned short* opwT = gw1T + (size_t)1024 * 1024;
    unsigned short* xb   = opwT + (size_t)1024 * 1024;               // 8192x1024 bf16 (x, later v2)
    float* V             = (float*)(xb + (size_t)8192 * 1024);       // 8192x1024 f32 (v0, v1)
    unsigned short* ctrlB= (unsigned short*)(V + (size_t)8192 * 1024); // 8192x2048 bf16
    unsigned short* xcB  = ctrlB + (size_t)8192 * 2048;              // 8192x1024 bf16
    float* vconv         = out;                                      // d_out as f32 scratch

    dim3 blk(256);
    dim3 gconv(LL / CTT, DD / CCC, BB);

    // conversions
    cvt_bf16_kernel<<<4096, blk, 0, stream>>>(x, xb);
    wtrans_kernel<<<dim3(96, 32), blk, 0, stream>>>(ipw, ipwT, 1024, 3072);
    wtrans_kernel<<<dim3(32, 32), blk, 0, stream>>>(gw, gw0T, 1024, 1024);
    wtrans_kernel<<<dim3(32, 32), blk, 0, stream>>>(gw + (size_t)1024 * 1024, gw1T, 1024, 1024);
    wtrans_kernel<<<dim3(32, 32), blk, 0, stream>>>(opw, opwT, 1024, 1024);

    // implicit filters
    filter_kernel<<<NORD * TAPS, blk, 0, stream>>>(freqs, w1, b1, w2, b2, w3, b3, decay, h);

    // fused in_proj: cols<1024 -> V (f32), cols>=1024 -> ctrlB (bf16)
    gemm_bf16_kernel<4><<<1536, blk, 0, stream>>>(xb, ipwT, ipb, nullptr, V, 24, 1024, 1024, ctrlB);

    // order 0
    causal_conv_kernel<<<gconv, blk, 0, stream>>>(V, h, vconv);
    dwconv_bf16_kernel<<<4096, blk, 0, stream>>>(ctrlB, 2048, cw, cb, xcB);
    gemm_bf16_kernel<2><<<512, blk, 0, stream>>>(xcB, gw0T, gb, vconv, V, 8, 1024, 1024, nullptr);

    // order 1
    causal_conv_kernel<<<gconv, blk, 0, stream>>>(V, h + (size_t)TAPS * DD, vconv);
    dwconv_bf16_kernel<<<4096, blk, 0, stream>>>(ctrlB + 1024, 2048, cw + (size_t)KW * DD, cb + DD, xcB);
    gemm_bf16_kernel<3><<<512, blk, 0, stream>>>(xcB, gw1T, gb + DD, vconv, xb, 8, 1024, 1024, nullptr);

    // out = v2 @ opw + opb
    gemm_bf16_kernel<0><<<512, blk, 0, stream>>>(xb, opwT, opb, nullptr, out, 8, 1024, 1024, nullptr);
}

// Round 4
// 270.286 us; speedup vs baseline: 5.9755x; 1.1499x over previous
//
#include <hip/hip_runtime.h>
#include <math.h>

#define BB 2
#define LL 4096
#define DD 1024
#define NORD 2
#define NEMB 3
#define NFO 64
#define KW 3
#define TAPS 64    // window=exp(-0.5*n) -> e^-32 at n=64; exact truncation in f32

typedef __attribute__((ext_vector_type(8))) short bf16x8;
typedef __attribute__((ext_vector_type(4))) float f32x4;

__device__ __forceinline__ void gl_lds16(const void* g, void* s) {
    __builtin_amdgcn_global_load_lds(
        (const __attribute__((address_space(1))) void*)g,
        (__attribute__((address_space(3))) void*)s, 16, 0, 0);
}

__device__ __forceinline__ float bf2f(unsigned short u) {
    union { unsigned int i; float f; } v; v.i = ((unsigned int)u) << 16; return v.f;
}
__device__ __forceinline__ unsigned short f2bf(float f) {
    union { float f; unsigned int i; } v; v.f = f;
    unsigned int r = v.i + 0x7FFF + ((v.i >> 16) & 1);   // round-nearest-even
    return (unsigned short)(r >> 16);
}

__device__ __forceinline__ float gelu_exact(float x) {
    return 0.5f * x * (1.0f + erff(x * 0.70710678118654752440f));
}

// ---------------------------------------------------------------------------
// f32 -> bf16 bulk convert (8 elems / thread)
// ---------------------------------------------------------------------------
__global__ __launch_bounds__(256) void cvt_bf16_kernel(
    const float* __restrict__ src, unsigned short* __restrict__ dst)
{
    size_t i = ((size_t)blockIdx.x * 256 + threadIdx.x) * 8;
    float4 a = *(const float4*)(src + i);
    float4 b = *(const float4*)(src + i + 4);
    bf16x8 o;
    o[0] = (short)f2bf(a.x); o[1] = (short)f2bf(a.y); o[2] = (short)f2bf(a.z); o[3] = (short)f2bf(a.w);
    o[4] = (short)f2bf(b.x); o[5] = (short)f2bf(b.y); o[6] = (short)f2bf(b.z); o[7] = (short)f2bf(b.w);
    *(bf16x8*)(dst + i) = o;
}

// ---------------------------------------------------------------------------
// Weight transpose+convert: src (K x N f32, row-major) -> dst (N x K bf16)
// ---------------------------------------------------------------------------
__global__ __launch_bounds__(256) void wtrans_kernel(
    const float* __restrict__ src, unsigned short* __restrict__ dst, int K, int N)
{
    __shared__ float t[32][33];
    const int n0 = blockIdx.x * 32;
    const int k0 = blockIdx.y * 32;
    const int tid = threadIdx.x;
    const int r = tid >> 5;       // 0..7
    const int c = tid & 31;
    #pragma unroll
    for (int p = 0; p < 4; ++p)
        t[r + p * 8][c] = src[(size_t)(k0 + r + p * 8) * N + n0 + c];
    __syncthreads();
    #pragma unroll
    for (int p = 0; p < 4; ++p)
        dst[(size_t)(n0 + r + p * 8) * K + k0 + c] = f2bf(t[c][r + p * 8]);
}

// ---------------------------------------------------------------------------
// Implicit filter: h[i][n][c] for n in [0,TAPS). One block per (i,n).
// ---------------------------------------------------------------------------
__global__ __launch_bounds__(256) void filter_kernel(
    const float* __restrict__ freqs, const float* __restrict__ w1, const float* __restrict__ b1,
    const float* __restrict__ w2, const float* __restrict__ b2,
    const float* __restrict__ w3, const float* __restrict__ b3,
    const float* __restrict__ decay, float* __restrict__ hout)
{
    const int i = blockIdx.x / TAPS;
    const int n = blockIdx.x % TAPS;
    const int tid = threadIdx.x;
    const float t = (float)n / (float)(LL - 1);

    __shared__ float s1[NFO];
    __shared__ float s2[NFO];

    if (tid < NFO) {
        float enc[7];
        const float* fr = freqs + i * NEMB;
        const float c2pi = 6.28318530717958647692f;
        #pragma unroll
        for (int e = 0; e < 3; ++e) {
            float a = c2pi * fr[e] * t;
            enc[e]     = sinf(a);
            enc[e + 3] = cosf(a);
        }
        enc[6] = t;
        const float* w = w1 + i * 7 * NFO;
        float acc = b1[i * NFO + tid];
        #pragma unroll
        for (int e = 0; e < 7; ++e) acc += enc[e] * w[e * NFO + tid];
        s1[tid] = gelu_exact(acc);
    }
    __syncthreads();
    if (tid < NFO) {
        const float* w = w2 + i * NFO * NFO;
        float acc = b2[i * NFO + tid];
        #pragma unroll 8
        for (int g = 0; g < NFO; ++g) acc += s1[g] * w[g * NFO + tid];
        s2[tid] = gelu_exact(acc);
    }
    __syncthreads();

    const int c0 = tid * 4;
    const float* w = w3 + (size_t)i * NFO * DD + c0;
    float4 acc = *(const float4*)(b3 + (size_t)i * DD + c0);
    #pragma unroll 8
    for (int g = 0; g < NFO; ++g) {
        float hg = s2[g];
        float4 wv = *(const float4*)(w + (size_t)g * DD);
        acc.x += hg * wv.x; acc.y += hg * wv.y; acc.z += hg * wv.z; acc.w += hg * wv.w;
    }
    float4 dc = *(const float4*)(decay + (size_t)i * DD + c0);
    float tl = t * (float)LL;
    acc.x *= expf(-fabsf(dc.x) * tl);
    acc.y *= expf(-fabsf(dc.y) * tl);
    acc.z *= expf(-fabsf(dc.z) * tl);
    acc.w *= expf(-fabsf(dc.w) * tl);
    *(float4*)(hout + ((size_t)i * TAPS + n) * DD + c0) = acc;
}

// ---------------------------------------------------------------------------
// Causal 64-tap per-channel conv (f32 in, f32 out), move-free inner loop.
// ---------------------------------------------------------------------------
#define CTT 64
#define CCC 32
__global__ __launch_bounds__(256) void causal_conv_kernel(
    const float* __restrict__ v, const float* __restrict__ hflt, float* __restrict__ y)
{
    const int t0 = blockIdx.x * CTT;
    const int c0 = blockIdx.y * CCC;
    const int b  = blockIdx.z;
    const int tid = threadIdx.x;

    __shared__ float sv[128][CCC];    // rows: t0-64 .. t0+63
    __shared__ float sh[TAPS][CCC];

    const float* vb = v + (size_t)b * LL * DD;
    #pragma unroll
    for (int q = 0; q < 4; ++q) {
        int idx = tid + q * 256;
        int row = idx >> 3;
        int c4  = (idx & 7) * 4;
        int t = t0 - 64 + row;
        float4 val = make_float4(0.f, 0.f, 0.f, 0.f);
        if (t >= 0) val = *(const float4*)(vb + (size_t)t * DD + c0 + c4);
        *(float4*)(&sv[row][c4]) = val;
    }
    #pragma unroll
    for (int q = 0; q < 2; ++q) {
        int idx = tid + q * 256;
        int u   = idx >> 3;
        int c4  = (idx & 7) * 4;
        *(float4*)(&sh[u][c4]) = *(const float4*)(hflt + (size_t)u * DD + c0 + c4);
    }
    __syncthreads();

    const int tx = tid & 31;
    const int ty = tid >> 5;
    const int R0 = 64 + ty * 8;

    float acc[8] = {};
    #pragma unroll
    for (int m = 0; m < 8; ++m) {
        float W[15];
        #pragma unroll
        for (int p = 0; p < 15; ++p) W[p] = sv[R0 - 8 * m - 7 + p][tx];
        float h8[8];
        #pragma unroll
        for (int du = 0; du < 8; ++du) h8[du] = sh[8 * m + du][tx];
        #pragma unroll
        for (int du = 0; du < 8; ++du)
            #pragma unroll
            for (int j = 0; j < 8; ++j)
                acc[j] += h8[du] * W[7 + j - du];
    }

    float* yb = y + ((size_t)b * LL + t0) * DD + c0;
    #pragma unroll
    for (int j = 0; j < 8; ++j) yb[(size_t)(ty * 8 + j) * DD + tx] = acc[j];
}

// ---------------------------------------------------------------------------
// Depthwise K=3 conv, bf16 in -> bf16 out. ctrl has leading dim `ld`.
// ---------------------------------------------------------------------------
__global__ __launch_bounds__(256) void dwconv_bf16_kernel(
    const unsigned short* __restrict__ ctrl, int ld,
    const float* __restrict__ cw, const float* __restrict__ cb,
    unsigned short* __restrict__ xc)
{
    size_t idx = (size_t)blockIdx.x * 256 + threadIdx.x;
    int c8 = (int)(idx & 127) * 8;
    size_t bt = idx >> 7;
    int t = (int)(bt & (LL - 1));

    const unsigned short* base = ctrl + bt * ld + c8;
    bf16x8 xm = {}, xp = {};
    bf16x8 x0 = *(const bf16x8*)(base);
    if (t > 0)      xm = *(const bf16x8*)(base - ld);
    if (t < LL - 1) xp = *(const bf16x8*)(base + ld);

    bf16x8 o;
    #pragma unroll
    for (int q = 0; q < 8; ++q) {
        int c = c8 + q;
        float r = cw[0 * DD + c] * bf2f((unsigned short)xm[q])
                + cw[1 * DD + c] * bf2f((unsigned short)x0[q])
                + cw[2 * DD + c] * bf2f((unsigned short)xp[q])
                + cb[c];
        o[q] = (short)f2bf(r);
    }
    *(bf16x8*)(xc + bt * DD + c8) = o;
}

// ---------------------------------------------------------------------------
// bf16 MFMA GEMM, T3/T4/T5 structure: C = A(Mx1024) @ BT(Nx1024)^T + bias
// BM=256 x BN(256|128) tile, BK=64, 8 waves (512 thr), double-buffered LDS,
// raw barriers + counted vmcnt (loads for tile t+2 in flight across tile t+1),
// setprio around MFMA clusters. LDS in m97-style [128][32] chunks, slot-XOR
// swizzle on both sides (0 bank conflicts, measured).
// EPI 0: f32 store   2: f32 v=vconv*xc*sigmoid(acc+b)   3: same, bf16 store
// EPI 4: split: col<1024 -> f32 Cout (ldc 1024); else bf16 Cout2 (ldc 2048)
// ---------------------------------------------------------------------------
template <int BN, int EPI>
__global__ __launch_bounds__(512) void gemm256_kernel(
    const unsigned short* __restrict__ A,    // M x 1024
    const unsigned short* __restrict__ BT,   // N x 1024
    const float* __restrict__ bias,          // N
    const float* __restrict__ vconv,         // M x 1024 f32 (EPI 2/3)
    void* __restrict__ Cout,
    int Nblk,
    void* __restrict__ Cout2)
{
    constexpr int NW_N   = BN / 64;          // waves along N (4 or 2)
    constexpr int NW_M   = 8 / NW_N;         // waves along M (2 or 4)
    constexpr int WM     = 256 / NW_M;       // per-wave rows (128 or 64)
    constexpr int M_REP  = WM / 16;          // m-frags (8 or 4)
    constexpr int BCH    = BN / 128;         // B row-halves (2 or 1)
    constexpr int LDSBUF = 32768 + BN * 128; // bytes per K-tile buffer
    constexpr int NLOADS = 4 + 2 * BCH;      // gl_lds per tile per wave

    __shared__ char lds[2 * LDSBUF];

    const int tid  = threadIdx.x;
    const int wave = tid >> 6;
    const int lane = tid & 63;

    // bijective XCD swizzle (grid % 8 == 0 for all launches)
    const int nwg  = gridDim.x;
    const int orig = blockIdx.x;
    const int wg   = (orig & 7) * (nwg >> 3) + (orig >> 3);
    const int by   = wg / Nblk;
    const int bx   = wg % Nblk;

    const int wm  = (wave / NW_N) * WM;
    const int wn  = (wave % NW_N) * 64;
    const int llo = lane & 15;
    const int lhi = lane >> 4;

    // ---- staging source addresses (pre-swizzled slot) ----
    const int crow = tid >> 2;               // 0..127 within chunk
    const int csl  = tid & 3;
    const int csrc = csl ^ ((crow >> 1) & 3);
    const unsigned short* Asrc = A  + (size_t)(by * 256 + crow) * 1024 + csrc * 8;
    const unsigned short* Bsrc = BT + (size_t)(bx * BN  + crow) * 1024 + csrc * 8;
    char* ldsp = (char*)lds;
    const int wofs = wave * 1024;            // wave-uniform dest base within chunk

    // ---- ds_read byte offsets (within a buffer) ----
    const int slot = lhi ^ ((llo >> 1) & 3);
    int offA[M_REP], offB[4];
    #pragma unroll
    for (int mi = 0; mi < M_REP; ++mi) {
        int rowA = wm + mi * 16 + llo;
        offA[mi] = (rowA >> 7) * 16384 + (rowA & 127) * 64 + slot * 16;
    }
    #pragma unroll
    for (int ni = 0; ni < 4; ++ni) {
        int rowB = wn + ni * 16 + llo;
        offB[ni] = 32768 + (rowB >> 7) * 16384 + (rowB & 127) * 64 + slot * 16;
    }

    f32x4 acc[M_REP][4] = {};

    auto stage = [&](int t) {
        const int bo = (t & 1) * LDSBUF;
        const int k0 = t * 64;
        #pragma unroll
        for (int rh = 0; rh < 2; ++rh)
            #pragma unroll
            for (int kh = 0; kh < 2; ++kh)
                gl_lds16(Asrc + (size_t)rh * 128 * 1024 + kh * 32 + k0,
                         ldsp + bo + (rh * 2 + kh) * 8192 + wofs);
        #pragma unroll
        for (int rh = 0; rh < BCH; ++rh)
            #pragma unroll
            for (int kh = 0; kh < 2; ++kh)
                gl_lds16(Bsrc + (size_t)rh * 128 * 1024 + kh * 32 + k0,
                         ldsp + bo + 32768 + (rh * 2 + kh) * 8192 + wofs);
    };

    // prologue: tiles 0 and 1 in flight; wait for tile 0
    stage(0);
    stage(1);
    if constexpr (NLOADS == 8) asm volatile("s_waitcnt vmcnt(8)" ::: "memory");
    else                       asm volatile("s_waitcnt vmcnt(6)" ::: "memory");
    __builtin_amdgcn_sched_barrier(0);
    __builtin_amdgcn_s_barrier();
    __builtin_amdgcn_sched_barrier(0);

    for (int t = 0; t < 16; ++t) {
        const int bo = (t & 1) * LDSBUF;
        #pragma unroll
        for (int kh = 0; kh < 2; ++kh) {
            bf16x8 af[M_REP], bfr[4];
            #pragma unroll
            for (int mi = 0; mi < M_REP; ++mi)
                af[mi] = *(const bf16x8*)(ldsp + bo + offA[mi] + kh * 8192);
            #pragma unroll
            for (int ni = 0; ni < 4; ++ni)
                bfr[ni] = *(const bf16x8*)(ldsp + bo + offB[ni] + kh * 8192);
            __builtin_amdgcn_s_setprio(1);
            #pragma unroll
            for (int mi = 0; mi < M_REP; ++mi)
                #pragma unroll
                for (int ni = 0; ni < 4; ++ni)
                    acc[mi][ni] = __builtin_amdgcn_mfma_f32_16x16x32_bf16(af[mi], bfr[ni], acc[mi][ni], 0, 0, 0);
            __builtin_amdgcn_s_setprio(0);
        }
        // all waves done reading buf[t&1] (reads consumed by MFMAs above)
        __builtin_amdgcn_s_barrier();
        __builtin_amdgcn_sched_barrier(0);
        if (t + 2 < 16) {
            stage(t + 2);                    // into buf[t&1], just released
            if constexpr (NLOADS == 8) asm volatile("s_waitcnt vmcnt(8)" ::: "memory");
            else                       asm volatile("s_waitcnt vmcnt(6)" ::: "memory");
        } else {
            asm volatile("s_waitcnt vmcnt(0)" ::: "memory");
        }
        __builtin_amdgcn_sched_barrier(0);
        __builtin_amdgcn_s_barrier();
        __builtin_amdgcn_sched_barrier(0);
    }

    // ---- epilogue: C/D layout col=lane&15, row=(lane>>4)*4+reg ----
    #pragma unroll
    for (int ni = 0; ni < 4; ++ni) {
        const int col = bx * BN + wn + ni * 16 + llo;
        const float bj = bias[col];
        #pragma unroll
        for (int mi = 0; mi < M_REP; ++mi) {
            #pragma unroll
            for (int r = 0; r < 4; ++r) {
                const int rowg = by * 256 + wm + mi * 16 + lhi * 4 + r;
                float v = acc[mi][ni][r] + bj;
                if (EPI == 0) {
                    ((float*)Cout)[(size_t)rowg * 1024 + col] = v;
                } else if (EPI == 4) {
                    if (col < 1024) ((float*)Cout)[(size_t)rowg * 1024 + col] = v;
                    else ((unsigned short*)Cout2)[(size_t)rowg * 2048 + (col - 1024)] = f2bf(v);
                } else {
                    float xc = bf2f(A[(size_t)rowg * 1024 + col]);
                    float vc = vconv[(size_t)rowg * 1024 + col];
                    float o  = vc * xc * (1.0f / (1.0f + expf(-v)));
                    if (EPI == 2) ((float*)Cout)[(size_t)rowg * 1024 + col] = o;
                    else          ((unsigned short*)Cout)[(size_t)rowg * 1024 + col] = f2bf(o);
                }
            }
        }
    }
}

// ---------------------------------------------------------------------------
extern "C" void kernel_launch(void* const* d_in, const int* in_sizes, int n_in,
                              void* d_out, int out_size, void* d_ws, size_t ws_size,
                              hipStream_t stream) {
    const float* x     = (const float*)d_in[0];
    const float* ipw   = (const float*)d_in[1];
    const float* ipb   = (const float*)d_in[2];
    const float* opw   = (const float*)d_in[3];
    const float* opb   = (const float*)d_in[4];
    const float* freqs = (const float*)d_in[5];
    const float* w1    = (const float*)d_in[6];
    const float* b1    = (const float*)d_in[7];
    const float* w2    = (const float*)d_in[8];
    const float* b2    = (const float*)d_in[9];
    const float* w3    = (const float*)d_in[10];
    const float* b3    = (const float*)d_in[11];
    const float* decay = (const float*)d_in[12];
    const float* cw    = (const float*)d_in[13];
    const float* cb    = (const float*)d_in[14];
    const float* gw    = (const float*)d_in[15];
    const float* gb    = (const float*)d_in[16];
    float* out = (float*)d_out;

    // workspace layout
    char* w = (char*)d_ws;
    float* h             = (float*)w;                                // NORD*TAPS*DD f32
    unsigned short* ipwT = (unsigned short*)(w + (size_t)1048576);   // 3072x1024 bf16
    unsigned short* gw0T = ipwT + (size_t)3072 * 1024;               // 1024x1024
    unsigned short* gw1T = gw0T + (size_t)1024 * 1024;
    unsigned short* opwT = gw1T + (size_t)1024 * 1024;
    unsigned short* xb   = opwT + (size_t)1024 * 1024;               // 8192x1024 bf16 (x, later v2)
    float* V             = (float*)(xb + (size_t)8192 * 1024);       // 8192x1024 f32 (v0, v1)
    unsigned short* ctrlB= (unsigned short*)(V + (size_t)8192 * 1024); // 8192x2048 bf16
    unsigned short* xcB  = ctrlB + (size_t)8192 * 2048;              // 8192x1024 bf16
    float* vconv         = out;                                      // d_out as f32 scratch

    dim3 blk(256);
    dim3 blk512(512);
    dim3 gconv(LL / CTT, DD / CCC, BB);

    // conversions
    cvt_bf16_kernel<<<4096, blk, 0, stream>>>(x, xb);
    wtrans_kernel<<<dim3(96, 32), blk, 0, stream>>>(ipw, ipwT, 1024, 3072);
    wtrans_kernel<<<dim3(32, 32), blk, 0, stream>>>(gw, gw0T, 1024, 1024);
    wtrans_kernel<<<dim3(32, 32), blk, 0, stream>>>(gw + (size_t)1024 * 1024, gw1T, 1024, 1024);
    wtrans_kernel<<<dim3(32, 32), blk, 0, stream>>>(opw, opwT, 1024, 1024);

    // implicit filters
    filter_kernel<<<NORD * TAPS, blk, 0, stream>>>(freqs, w1, b1, w2, b2, w3, b3, decay, h);

    // fused in_proj: cols<1024 -> V (f32), cols>=1024 -> ctrlB (bf16)
    gemm256_kernel<256, 4><<<384, blk512, 0, stream>>>(xb, ipwT, ipb, nullptr, V, 12, ctrlB);

    // order 0
    causal_conv_kernel<<<gconv, blk, 0, stream>>>(V, h, vconv);
    dwconv_bf16_kernel<<<4096, blk, 0, stream>>>(ctrlB, 2048, cw, cb, xcB);
    gemm256_kernel<128, 2><<<256, blk512, 0, stream>>>(xcB, gw0T, gb, vconv, V, 8, nullptr);

    // order 1
    causal_conv_kernel<<<gconv, blk, 0, stream>>>(V, h + (size_t)TAPS * DD, vconv);
    dwconv_bf16_kernel<<<4096, blk, 0, stream>>>(ctrlB + 1024, 2048, cw + (size_t)KW * DD, cb + DD, xcB);
    gemm256_kernel<128, 3><<<256, blk512, 0, stream>>>(xcB, gw1T, gb + DD, vconv, xb, 8, nullptr);

    // out = v2 @ opw + opb
    gemm256_kernel<128, 0><<<256, blk512, 0, stream>>>(xb, opwT, opb, nullptr, out, 8, nullptr);
}

// Round 5
// 259.199 us; speedup vs baseline: 6.2311x; 1.0428x over previous
//
#include <hip/hip_runtime.h>
#include <math.h>

#define BB 2
#define LL 4096
#define DD 1024
#define NORD 2
#define NEMB 3
#define NFO 64
#define KW 3
#define TAPS 64    // window=exp(-0.5*n) -> e^-32 at n=64; exact truncation in f32

typedef __attribute__((ext_vector_type(8))) short bf16x8;
typedef __attribute__((ext_vector_type(4))) float f32x4;

__device__ __forceinline__ void gl_lds16(const void* g, void* s) {
    __builtin_amdgcn_global_load_lds(
        (const __attribute__((address_space(1))) void*)g,
        (__attribute__((address_space(3))) void*)s, 16, 0, 0);
}

__device__ __forceinline__ float bf2f(unsigned short u) {
    union { unsigned int i; float f; } v; v.i = ((unsigned int)u) << 16; return v.f;
}
__device__ __forceinline__ unsigned short f2bf(float f) {
    union { float f; unsigned int i; } v; v.f = f;
    unsigned int r = v.i + 0x7FFF + ((v.i >> 16) & 1);   // round-nearest-even
    return (unsigned short)(r >> 16);
}

__device__ __forceinline__ float gelu_exact(float x) {
    return 0.5f * x * (1.0f + erff(x * 0.70710678118654752440f));
}

// ---------------------------------------------------------------------------
// f32 -> bf16 bulk convert (8 elems / thread)
// ---------------------------------------------------------------------------
__global__ __launch_bounds__(256) void cvt_bf16_kernel(
    const float* __restrict__ src, unsigned short* __restrict__ dst)
{
    size_t i = ((size_t)blockIdx.x * 256 + threadIdx.x) * 8;
    float4 a = *(const float4*)(src + i);
    float4 b = *(const float4*)(src + i + 4);
    bf16x8 o;
    o[0] = (short)f2bf(a.x); o[1] = (short)f2bf(a.y); o[2] = (short)f2bf(a.z); o[3] = (short)f2bf(a.w);
    o[4] = (short)f2bf(b.x); o[5] = (short)f2bf(b.y); o[6] = (short)f2bf(b.z); o[7] = (short)f2bf(b.w);
    *(bf16x8*)(dst + i) = o;
}

// ---------------------------------------------------------------------------
// Weight transpose+convert: src (K x N f32, row-major) -> dst (N x K bf16)
// ---------------------------------------------------------------------------
__global__ __launch_bounds__(256) void wtrans_kernel(
    const float* __restrict__ src, unsigned short* __restrict__ dst, int K, int N)
{
    __shared__ float t[32][33];
    const int n0 = blockIdx.x * 32;
    const int k0 = blockIdx.y * 32;
    const int tid = threadIdx.x;
    const int r = tid >> 5;       // 0..7
    const int c = tid & 31;
    #pragma unroll
    for (int p = 0; p < 4; ++p)
        t[r + p * 8][c] = src[(size_t)(k0 + r + p * 8) * N + n0 + c];
    __syncthreads();
    #pragma unroll
    for (int p = 0; p < 4; ++p)
        dst[(size_t)(n0 + r + p * 8) * K + k0 + c] = f2bf(t[c][r + p * 8]);
}

// ---------------------------------------------------------------------------
// Implicit filter: h[i][n][c] for n in [0,TAPS). One block per (i,n).
// ---------------------------------------------------------------------------
__global__ __launch_bounds__(256) void filter_kernel(
    const float* __restrict__ freqs, const float* __restrict__ w1, const float* __restrict__ b1,
    const float* __restrict__ w2, const float* __restrict__ b2,
    const float* __restrict__ w3, const float* __restrict__ b3,
    const float* __restrict__ decay, float* __restrict__ hout)
{
    const int i = blockIdx.x / TAPS;
    const int n = blockIdx.x % TAPS;
    const int tid = threadIdx.x;
    const float t = (float)n / (float)(LL - 1);

    __shared__ float s1[NFO];
    __shared__ float s2[NFO];

    if (tid < NFO) {
        float enc[7];
        const float* fr = freqs + i * NEMB;
        const float c2pi = 6.28318530717958647692f;
        #pragma unroll
        for (int e = 0; e < 3; ++e) {
            float a = c2pi * fr[e] * t;
            enc[e]     = sinf(a);
            enc[e + 3] = cosf(a);
        }
        enc[6] = t;
        const float* w = w1 + i * 7 * NFO;
        float acc = b1[i * NFO + tid];
        #pragma unroll
        for (int e = 0; e < 7; ++e) acc += enc[e] * w[e * NFO + tid];
        s1[tid] = gelu_exact(acc);
    }
    __syncthreads();
    if (tid < NFO) {
        const float* w = w2 + i * NFO * NFO;
        float acc = b2[i * NFO + tid];
        #pragma unroll 8
        for (int g = 0; g < NFO; ++g) acc += s1[g] * w[g * NFO + tid];
        s2[tid] = gelu_exact(acc);
    }
    __syncthreads();

    const int c0 = tid * 4;
    const float* w = w3 + (size_t)i * NFO * DD + c0;
    float4 acc = *(const float4*)(b3 + (size_t)i * DD + c0);
    #pragma unroll 8
    for (int g = 0; g < NFO; ++g) {
        float hg = s2[g];
        float4 wv = *(const float4*)(w + (size_t)g * DD);
        acc.x += hg * wv.x; acc.y += hg * wv.y; acc.z += hg * wv.z; acc.w += hg * wv.w;
    }
    float4 dc = *(const float4*)(decay + (size_t)i * DD + c0);
    float tl = t * (float)LL;
    acc.x *= expf(-fabsf(dc.x) * tl);
    acc.y *= expf(-fabsf(dc.y) * tl);
    acc.z *= expf(-fabsf(dc.z) * tl);
    acc.w *= expf(-fabsf(dc.w) * tl);
    *(float4*)(hout + ((size_t)i * TAPS + n) * DD + c0) = acc;
}

// ---------------------------------------------------------------------------
// Causal 64-tap per-channel conv (f32 in, f32 out), move-free inner loop.
// ---------------------------------------------------------------------------
#define CTT 64
#define CCC 32
__global__ __launch_bounds__(256) void causal_conv_kernel(
    const float* __restrict__ v, const float* __restrict__ hflt, float* __restrict__ y)
{
    const int t0 = blockIdx.x * CTT;
    const int c0 = blockIdx.y * CCC;
    const int b  = blockIdx.z;
    const int tid = threadIdx.x;

    __shared__ float sv[128][CCC];    // rows: t0-64 .. t0+63
    __shared__ float sh[TAPS][CCC];

    const float* vb = v + (size_t)b * LL * DD;
    #pragma unroll
    for (int q = 0; q < 4; ++q) {
        int idx = tid + q * 256;
        int row = idx >> 3;
        int c4  = (idx & 7) * 4;
        int t = t0 - 64 + row;
        float4 val = make_float4(0.f, 0.f, 0.f, 0.f);
        if (t >= 0) val = *(const float4*)(vb + (size_t)t * DD + c0 + c4);
        *(float4*)(&sv[row][c4]) = val;
    }
    #pragma unroll
    for (int q = 0; q < 2; ++q) {
        int idx = tid + q * 256;
        int u   = idx >> 3;
        int c4  = (idx & 7) * 4;
        *(float4*)(&sh[u][c4]) = *(const float4*)(hflt + (size_t)u * DD + c0 + c4);
    }
    __syncthreads();

    const int tx = tid & 31;
    const int ty = tid >> 5;
    const int R0 = 64 + ty * 8;

    float acc[8] = {};
    #pragma unroll
    for (int m = 0; m < 8; ++m) {
        float W[15];
        #pragma unroll
        for (int p = 0; p < 15; ++p) W[p] = sv[R0 - 8 * m - 7 + p][tx];
        float h8[8];
        #pragma unroll
        for (int du = 0; du < 8; ++du) h8[du] = sh[8 * m + du][tx];
        #pragma unroll
        for (int du = 0; du < 8; ++du)
            #pragma unroll
            for (int j = 0; j < 8; ++j)
                acc[j] += h8[du] * W[7 + j - du];
    }

    float* yb = y + ((size_t)b * LL + t0) * DD + c0;
    #pragma unroll
    for (int j = 0; j < 8; ++j) yb[(size_t)(ty * 8 + j) * DD + tx] = acc[j];
}

// ---------------------------------------------------------------------------
// Depthwise K=3 conv, bf16 in -> bf16 out. ctrl has leading dim `ld`.
// ---------------------------------------------------------------------------
__global__ __launch_bounds__(256) void dwconv_bf16_kernel(
    const unsigned short* __restrict__ ctrl, int ld,
    const float* __restrict__ cw, const float* __restrict__ cb,
    unsigned short* __restrict__ xc)
{
    size_t idx = (size_t)blockIdx.x * 256 + threadIdx.x;
    int c8 = (int)(idx & 127) * 8;
    size_t bt = idx >> 7;
    int t = (int)(bt & (LL - 1));

    const unsigned short* base = ctrl + bt * ld + c8;
    bf16x8 xm = {}, xp = {};
    bf16x8 x0 = *(const bf16x8*)(base);
    if (t > 0)      xm = *(const bf16x8*)(base - ld);
    if (t < LL - 1) xp = *(const bf16x8*)(base + ld);

    bf16x8 o;
    #pragma unroll
    for (int q = 0; q < 8; ++q) {
        int c = c8 + q;
        float r = cw[0 * DD + c] * bf2f((unsigned short)xm[q])
                + cw[1 * DD + c] * bf2f((unsigned short)x0[q])
                + cw[2 * DD + c] * bf2f((unsigned short)xp[q])
                + cb[c];
        o[q] = (short)f2bf(r);
    }
    *(bf16x8*)(xc + bt * DD + c8) = o;
}

// ---------------------------------------------------------------------------
// bf16 MFMA GEMM (512 thr, BM=256): kept from round 4 for gates/out_proj.
// ---------------------------------------------------------------------------
template <int BN, int EPI>
__global__ __launch_bounds__(512) void gemm256_kernel(
    const unsigned short* __restrict__ A,    // M x 1024
    const unsigned short* __restrict__ BT,   // N x 1024
    const float* __restrict__ bias,          // N
    const float* __restrict__ vconv,         // M x 1024 f32 (EPI 2/3)
    void* __restrict__ Cout,
    int Nblk,
    void* __restrict__ Cout2)
{
    constexpr int NW_N   = BN / 64;
    constexpr int NW_M   = 8 / NW_N;
    constexpr int WM     = 256 / NW_M;
    constexpr int M_REP  = WM / 16;
    constexpr int BCH    = BN / 128;
    constexpr int LDSBUF = 32768 + BN * 128;
    constexpr int NLOADS = 4 + 2 * BCH;

    __shared__ char lds[2 * LDSBUF];

    const int tid  = threadIdx.x;
    const int wave = tid >> 6;
    const int lane = tid & 63;

    const int nwg  = gridDim.x;
    const int orig = blockIdx.x;
    const int wg   = (orig & 7) * (nwg >> 3) + (orig >> 3);
    const int by   = wg / Nblk;
    const int bx   = wg % Nblk;

    const int wm  = (wave / NW_N) * WM;
    const int wn  = (wave % NW_N) * 64;
    const int llo = lane & 15;
    const int lhi = lane >> 4;

    const int crow = tid >> 2;
    const int csl  = tid & 3;
    const int csrc = csl ^ ((crow >> 1) & 3);
    const unsigned short* Asrc = A  + (size_t)(by * 256 + crow) * 1024 + csrc * 8;
    const unsigned short* Bsrc = BT + (size_t)(bx * BN  + crow) * 1024 + csrc * 8;
    char* ldsp = (char*)lds;
    const int wofs = wave * 1024;

    const int slot = lhi ^ ((llo >> 1) & 3);
    int offA[M_REP], offB[4];
    #pragma unroll
    for (int mi = 0; mi < M_REP; ++mi) {
        int rowA = wm + mi * 16 + llo;
        offA[mi] = (rowA >> 7) * 16384 + (rowA & 127) * 64 + slot * 16;
    }
    #pragma unroll
    for (int ni = 0; ni < 4; ++ni) {
        int rowB = wn + ni * 16 + llo;
        offB[ni] = 32768 + (rowB >> 7) * 16384 + (rowB & 127) * 64 + slot * 16;
    }

    f32x4 acc[M_REP][4] = {};

    auto stage = [&](int t) {
        const int bo = (t & 1) * LDSBUF;
        const int k0 = t * 64;
        #pragma unroll
        for (int rh = 0; rh < 2; ++rh)
            #pragma unroll
            for (int kh = 0; kh < 2; ++kh)
                gl_lds16(Asrc + (size_t)rh * 128 * 1024 + kh * 32 + k0,
                         ldsp + bo + (rh * 2 + kh) * 8192 + wofs);
        #pragma unroll
        for (int rh = 0; rh < BCH; ++rh)
            #pragma unroll
            for (int kh = 0; kh < 2; ++kh)
                gl_lds16(Bsrc + (size_t)rh * 128 * 1024 + kh * 32 + k0,
                         ldsp + bo + 32768 + (rh * 2 + kh) * 8192 + wofs);
    };

    stage(0);
    stage(1);
    if constexpr (NLOADS == 8) asm volatile("s_waitcnt vmcnt(8)" ::: "memory");
    else                       asm volatile("s_waitcnt vmcnt(6)" ::: "memory");
    __builtin_amdgcn_sched_barrier(0);
    __builtin_amdgcn_s_barrier();
    __builtin_amdgcn_sched_barrier(0);

    for (int t = 0; t < 16; ++t) {
        const int bo = (t & 1) * LDSBUF;
        #pragma unroll
        for (int kh = 0; kh < 2; ++kh) {
            bf16x8 af[M_REP], bfr[4];
            #pragma unroll
            for (int mi = 0; mi < M_REP; ++mi)
                af[mi] = *(const bf16x8*)(ldsp + bo + offA[mi] + kh * 8192);
            #pragma unroll
            for (int ni = 0; ni < 4; ++ni)
                bfr[ni] = *(const bf16x8*)(ldsp + bo + offB[ni] + kh * 8192);
            __builtin_amdgcn_s_setprio(1);
            #pragma unroll
            for (int mi = 0; mi < M_REP; ++mi)
                #pragma unroll
                for (int ni = 0; ni < 4; ++ni)
                    acc[mi][ni] = __builtin_amdgcn_mfma_f32_16x16x32_bf16(af[mi], bfr[ni], acc[mi][ni], 0, 0, 0);
            __builtin_amdgcn_s_setprio(0);
        }
        __builtin_amdgcn_s_barrier();
        __builtin_amdgcn_sched_barrier(0);
        if (t + 2 < 16) {
            stage(t + 2);
            if constexpr (NLOADS == 8) asm volatile("s_waitcnt vmcnt(8)" ::: "memory");
            else                       asm volatile("s_waitcnt vmcnt(6)" ::: "memory");
        } else {
            asm volatile("s_waitcnt vmcnt(0)" ::: "memory");
        }
        __builtin_amdgcn_sched_barrier(0);
        __builtin_amdgcn_s_barrier();
        __builtin_amdgcn_sched_barrier(0);
    }

    #pragma unroll
    for (int ni = 0; ni < 4; ++ni) {
        const int col = bx * BN + wn + ni * 16 + llo;
        const float bj = bias[col];
        #pragma unroll
        for (int mi = 0; mi < M_REP; ++mi) {
            #pragma unroll
            for (int r = 0; r < 4; ++r) {
                const int rowg = by * 256 + wm + mi * 16 + lhi * 4 + r;
                float v = acc[mi][ni][r] + bj;
                if (EPI == 0) {
                    ((float*)Cout)[(size_t)rowg * 1024 + col] = v;
                } else if (EPI == 4) {
                    if (col < 1024) ((float*)Cout)[(size_t)rowg * 1024 + col] = v;
                    else ((unsigned short*)Cout2)[(size_t)rowg * 2048 + (col - 1024)] = f2bf(v);
                } else {
                    float xc = bf2f(A[(size_t)rowg * 1024 + col]);
                    float vc = vconv[(size_t)rowg * 1024 + col];
                    float o  = vc * xc * (1.0f / (1.0f + expf(-v)));
                    if (EPI == 2) ((float*)Cout)[(size_t)rowg * 1024 + col] = o;
                    else          ((unsigned short*)Cout)[(size_t)rowg * 1024 + col] = f2bf(o);
                }
            }
        }
    }
}

// ---------------------------------------------------------------------------
// in_proj GEMM: BM=256, BN=128, BK=32, 256 thr (4 waves 2Mx2N, per-wave
// 128x64 => 12 LDS reads / 32 MFMA), dbuf LDS 48KB => 2 blocks/CU resident.
// Counted vmcnt 2-tile-ahead. EPI4 split epilogue (V f32 / ctrl bf16).
// ---------------------------------------------------------------------------
template <int EPI>
__global__ __launch_bounds__(256, 2) void gemm_ip_kernel(
    const unsigned short* __restrict__ A,    // M x 1024
    const unsigned short* __restrict__ BT,   // N x 1024
    const float* __restrict__ bias,          // N
    const float* __restrict__ vconv,         // unused for EPI 0/4
    void* __restrict__ Cout,
    int Nblk,
    void* __restrict__ Cout2)
{
    constexpr int LDSBUF = 24576;            // A 16KB (2 chunks) + B 8KB

    __shared__ char lds[2 * LDSBUF];

    const int tid  = threadIdx.x;
    const int wave = tid >> 6;
    const int lane = tid & 63;

    const int nwg  = gridDim.x;
    const int orig = blockIdx.x;
    const int wg   = (orig & 7) * (nwg >> 3) + (orig >> 3);
    const int by   = wg / Nblk;
    const int bx   = wg % Nblk;

    const int wm  = (wave >> 1) * 128;       // 2 waves along M
    const int wn  = (wave & 1) * 64;         // 2 waves along N
    const int llo = lane & 15;
    const int lhi = lane >> 4;

    // staging: 6 issues x 4KB. Chunk layout [128 rows][4 slots x 16B].
    const int srow = tid >> 2;               // 0..63
    const int ssl  = tid & 3;
    const int ssrc = ssl ^ ((srow >> 1) & 3);   // same for row and row+64
    const unsigned short* Asrc = A  + (size_t)(by * 256 + srow) * 1024 + ssrc * 8;
    const unsigned short* Bsrc = BT + (size_t)(bx * 128 + srow) * 1024 + ssrc * 8;
    char* ldsp = (char*)lds;
    const int wofs = wave * 1024;            // wave-uniform dest base

    // ds_read offsets
    const int slot = lhi ^ ((llo >> 1) & 3);
    int offA[8], offB[4];
    #pragma unroll
    for (int mi = 0; mi < 8; ++mi) {
        int rowA = wm + mi * 16 + llo;       // 0..255
        offA[mi] = (rowA >> 7) * 8192 + (rowA & 127) * 64 + slot * 16;
    }
    #pragma unroll
    for (int ni = 0; ni < 4; ++ni) {
        int rowB = wn + ni * 16 + llo;       // 0..127
        offB[ni] = 16384 + rowB * 64 + slot * 16;
    }

    f32x4 acc[8][4] = {};

    auto stage = [&](int t) {
        const int bo = (t & 1) * LDSBUF;
        const int k0 = t * 32;
        #pragma unroll
        for (int i = 0; i < 4; ++i)          // A: chunk i>>1, half i&1
            gl_lds16(Asrc + (size_t)(i * 64) * 1024 + k0,
                     ldsp + bo + (i >> 1) * 8192 + (i & 1) * 4096 + wofs);
        #pragma unroll
        for (int i = 0; i < 2; ++i)          // B
            gl_lds16(Bsrc + (size_t)(i * 64) * 1024 + k0,
                     ldsp + bo + 16384 + i * 4096 + wofs);
    };

    stage(0);
    stage(1);
    asm volatile("s_waitcnt vmcnt(6)" ::: "memory");
    __builtin_amdgcn_sched_barrier(0);
    __builtin_amdgcn_s_barrier();
    __builtin_amdgcn_sched_barrier(0);

    for (int t = 0; t < 32; ++t) {
        const int bo = (t & 1) * LDSBUF;
        bf16x8 af[8], bfr[4];
        #pragma unroll
        for (int mi = 0; mi < 8; ++mi)
            af[mi] = *(const bf16x8*)(ldsp + bo + offA[mi]);
        #pragma unroll
        for (int ni = 0; ni < 4; ++ni)
            bfr[ni] = *(const bf16x8*)(ldsp + bo + offB[ni]);
        __builtin_amdgcn_s_setprio(1);
        #pragma unroll
        for (int mi = 0; mi < 8; ++mi)
            #pragma unroll
            for (int ni = 0; ni < 4; ++ni)
                acc[mi][ni] = __builtin_amdgcn_mfma_f32_16x16x32_bf16(af[mi], bfr[ni], acc[mi][ni], 0, 0, 0);
        __builtin_amdgcn_s_setprio(0);
        __builtin_amdgcn_s_barrier();
        __builtin_amdgcn_sched_barrier(0);
        if (t + 2 < 32) {
            stage(t + 2);
            asm volatile("s_waitcnt vmcnt(6)" ::: "memory");
        } else {
            asm volatile("s_waitcnt vmcnt(0)" ::: "memory");
        }
        __builtin_amdgcn_sched_barrier(0);
        __builtin_amdgcn_s_barrier();
        __builtin_amdgcn_sched_barrier(0);
    }

    // epilogue: C/D layout col=lane&15, row=(lane>>4)*4+reg
    #pragma unroll
    for (int ni = 0; ni < 4; ++ni) {
        const int col = bx * 128 + wn + ni * 16 + llo;
        const float bj = bias[col];
        #pragma unroll
        for (int mi = 0; mi < 8; ++mi) {
            #pragma unroll
            for (int r = 0; r < 4; ++r) {
                const int rowg = by * 256 + wm + mi * 16 + lhi * 4 + r;
                float v = acc[mi][ni][r] + bj;
                if (EPI == 0) {
                    ((float*)Cout)[(size_t)rowg * 1024 + col] = v;
                } else if (EPI == 4) {
                    if (col < 1024) ((float*)Cout)[(size_t)rowg * 1024 + col] = v;
                    else ((unsigned short*)Cout2)[(size_t)rowg * 2048 + (col - 1024)] = f2bf(v);
                }
            }
        }
    }
}

// ---------------------------------------------------------------------------
extern "C" void kernel_launch(void* const* d_in, const int* in_sizes, int n_in,
                              void* d_out, int out_size, void* d_ws, size_t ws_size,
                              hipStream_t stream) {
    const float* x     = (const float*)d_in[0];
    const float* ipw   = (const float*)d_in[1];
    const float* ipb   = (const float*)d_in[2];
    const float* opw   = (const float*)d_in[3];
    const float* opb   = (const float*)d_in[4];
    const float* freqs = (const float*)d_in[5];
    const float* w1    = (const float*)d_in[6];
    const float* b1    = (const float*)d_in[7];
    const float* w2    = (const float*)d_in[8];
    const float* b2    = (const float*)d_in[9];
    const float* w3    = (const float*)d_in[10];
    const float* b3    = (const float*)d_in[11];
    const float* decay = (const float*)d_in[12];
    const float* cw    = (const float*)d_in[13];
    const float* cb    = (const float*)d_in[14];
    const float* gw    = (const float*)d_in[15];
    const float* gb    = (const float*)d_in[16];
    float* out = (float*)d_out;

    // workspace layout
    char* w = (char*)d_ws;
    float* h             = (float*)w;                                // NORD*TAPS*DD f32
    unsigned short* ipwT = (unsigned short*)(w + (size_t)1048576);   // 3072x1024 bf16
    unsigned short* gw0T = ipwT + (size_t)3072 * 1024;               // 1024x1024
    unsigned short* gw1T = gw0T + (size_t)1024 * 1024;
    unsigned short* opwT = gw1T + (size_t)1024 * 1024;
    unsigned short* xb   = opwT + (size_t)1024 * 1024;               // 8192x1024 bf16 (x, later v2)
    float* V             = (float*)(xb + (size_t)8192 * 1024);       // 8192x1024 f32 (v0, v1)
    unsigned short* ctrlB= (unsigned short*)(V + (size_t)8192 * 1024); // 8192x2048 bf16
    unsigned short* xcB  = ctrlB + (size_t)8192 * 2048;              // 8192x1024 bf16
    float* vconv         = out;                                      // d_out as f32 scratch

    dim3 blk(256);
    dim3 blk512(512);
    dim3 gconv(LL / CTT, DD / CCC, BB);

    // conversions
    cvt_bf16_kernel<<<4096, blk, 0, stream>>>(x, xb);
    wtrans_kernel<<<dim3(96, 32), blk, 0, stream>>>(ipw, ipwT, 1024, 3072);
    wtrans_kernel<<<dim3(32, 32), blk, 0, stream>>>(gw, gw0T, 1024, 1024);
    wtrans_kernel<<<dim3(32, 32), blk, 0, stream>>>(gw + (size_t)1024 * 1024, gw1T, 1024, 1024);
    wtrans_kernel<<<dim3(32, 32), blk, 0, stream>>>(opw, opwT, 1024, 1024);

    // implicit filters
    filter_kernel<<<NORD * TAPS, blk, 0, stream>>>(freqs, w1, b1, w2, b2, w3, b3, decay, h);

    // fused in_proj: cols<1024 -> V (f32), cols>=1024 -> ctrlB (bf16)
    gemm_ip_kernel<4><<<768, blk, 0, stream>>>(xb, ipwT, ipb, nullptr, V, 24, ctrlB);

    // order 0
    causal_conv_kernel<<<gconv, blk, 0, stream>>>(V, h, vconv);
    dwconv_bf16_kernel<<<4096, blk, 0, stream>>>(ctrlB, 2048, cw, cb, xcB);
    gemm256_kernel<128, 2><<<256, blk512, 0, stream>>>(xcB, gw0T, gb, vconv, V, 8, nullptr);

    // order 1
    causal_conv_kernel<<<gconv, blk, 0, stream>>>(V, h + (size_t)TAPS * DD, vconv);
    dwconv_bf16_kernel<<<4096, blk, 0, stream>>>(ctrlB + 1024, 2048, cw + (size_t)KW * DD, cb + DD, xcB);
    gemm256_kernel<128, 3><<<256, blk512, 0, stream>>>(xcB, gw1T, gb + DD, vconv, xb, 8, nullptr);

    // out = v2 @ opw + opb
    gemm256_kernel<128, 0><<<256, blk512, 0, stream>>>(xb, opwT, opb, nullptr, out, 8, nullptr);
}

// Round 6
// 228.495 us; speedup vs baseline: 7.0684x; 1.1344x over previous
//
#include <hip/hip_runtime.h>
#include <math.h>

#define BB 2
#define LL 4096
#define DD 1024
#define NORD 2
#define NEMB 3
#define NFO 64
#define KW 3
#define TAPS 64    // window=exp(-0.5*n) -> e^-32 at n=64; exact truncation in f32

typedef __attribute__((ext_vector_type(8))) short bf16x8;
typedef __attribute__((ext_vector_type(4))) float f32x4;

__device__ __forceinline__ void gl_lds16(const void* g, void* s) {
    __builtin_amdgcn_global_load_lds(
        (const __attribute__((address_space(1))) void*)g,
        (__attribute__((address_space(3))) void*)s, 16, 0, 0);
}

__device__ __forceinline__ float bf2f(unsigned short u) {
    union { unsigned int i; float f; } v; v.i = ((unsigned int)u) << 16; return v.f;
}
__device__ __forceinline__ unsigned short f2bf(float f) {
    union { float f; unsigned int i; } v; v.f = f;
    unsigned int r = v.i + 0x7FFF + ((v.i >> 16) & 1);   // round-nearest-even
    return (unsigned short)(r >> 16);
}

__device__ __forceinline__ float gelu_exact(float x) {
    return 0.5f * x * (1.0f + erff(x * 0.70710678118654752440f));
}

// ---------------------------------------------------------------------------
// Fused prep kernel: block ranges do
//   [0,4096)        : x f32 -> bf16
//   [4096,7168)     : ipw transpose  (K=1024, N=3072)
//   [7168,8192)     : gw0 transpose
//   [8192,9216)     : gw1 transpose
//   [9216,10240)    : opw transpose
//   [10240,10368)   : implicit filter (2 orders x 64 taps)
// ---------------------------------------------------------------------------
__device__ void wtrans_dev(const float* __restrict__ src, unsigned short* __restrict__ dst,
                           int K, int N, int bx, int by, int tid)
{
    __shared__ float t[32][33];
    const int n0 = bx * 32;
    const int k0 = by * 32;
    const int r = tid >> 5;
    const int c = tid & 31;
    #pragma unroll
    for (int p = 0; p < 4; ++p)
        t[r + p * 8][c] = src[(size_t)(k0 + r + p * 8) * N + n0 + c];
    __syncthreads();
    #pragma unroll
    for (int p = 0; p < 4; ++p)
        dst[(size_t)(n0 + r + p * 8) * K + k0 + c] = f2bf(t[c][r + p * 8]);
}

__global__ __launch_bounds__(256) void prep_kernel(
    const float* __restrict__ x, unsigned short* __restrict__ xb,
    const float* __restrict__ ipw, unsigned short* __restrict__ ipwT,
    const float* __restrict__ gw, unsigned short* __restrict__ gw0T, unsigned short* __restrict__ gw1T,
    const float* __restrict__ opw, unsigned short* __restrict__ opwT,
    const float* __restrict__ freqs, const float* __restrict__ w1, const float* __restrict__ b1,
    const float* __restrict__ w2, const float* __restrict__ b2,
    const float* __restrict__ w3, const float* __restrict__ b3,
    const float* __restrict__ decay, float* __restrict__ hout)
{
    const int bid = blockIdx.x;
    const int tid = threadIdx.x;

    if (bid < 4096) {
        size_t i = ((size_t)bid * 256 + tid) * 8;
        float4 a = *(const float4*)(x + i);
        float4 b = *(const float4*)(x + i + 4);
        bf16x8 o;
        o[0] = (short)f2bf(a.x); o[1] = (short)f2bf(a.y); o[2] = (short)f2bf(a.z); o[3] = (short)f2bf(a.w);
        o[4] = (short)f2bf(b.x); o[5] = (short)f2bf(b.y); o[6] = (short)f2bf(b.z); o[7] = (short)f2bf(b.w);
        *(bf16x8*)(xb + i) = o;
        return;
    }
    if (bid < 7168) { int q = bid - 4096; wtrans_dev(ipw, ipwT, 1024, 3072, q % 96, q / 96, tid); return; }
    if (bid < 8192) { int q = bid - 7168; wtrans_dev(gw, gw0T, 1024, 1024, q % 32, q / 32, tid); return; }
    if (bid < 9216) { int q = bid - 8192; wtrans_dev(gw + (size_t)1024 * 1024, gw1T, 1024, 1024, q % 32, q / 32, tid); return; }
    if (bid < 10240) { int q = bid - 9216; wtrans_dev(opw, opwT, 1024, 1024, q % 32, q / 32, tid); return; }

    // implicit filter
    const int q = bid - 10240;
    const int i = q / TAPS;
    const int n = q % TAPS;
    const float t = (float)n / (float)(LL - 1);

    __shared__ float s1[NFO];
    __shared__ float s2[NFO];

    if (tid < NFO) {
        float enc[7];
        const float* fr = freqs + i * NEMB;
        const float c2pi = 6.28318530717958647692f;
        #pragma unroll
        for (int e = 0; e < 3; ++e) {
            float a = c2pi * fr[e] * t;
            enc[e]     = sinf(a);
            enc[e + 3] = cosf(a);
        }
        enc[6] = t;
        const float* w = w1 + i * 7 * NFO;
        float acc = b1[i * NFO + tid];
        #pragma unroll
        for (int e = 0; e < 7; ++e) acc += enc[e] * w[e * NFO + tid];
        s1[tid] = gelu_exact(acc);
    }
    __syncthreads();
    if (tid < NFO) {
        const float* w = w2 + i * NFO * NFO;
        float acc = b2[i * NFO + tid];
        #pragma unroll 8
        for (int g = 0; g < NFO; ++g) acc += s1[g] * w[g * NFO + tid];
        s2[tid] = gelu_exact(acc);
    }
    __syncthreads();

    const int c0 = tid * 4;
    const float* w = w3 + (size_t)i * NFO * DD + c0;
    float4 acc = *(const float4*)(b3 + (size_t)i * DD + c0);
    #pragma unroll 8
    for (int g = 0; g < NFO; ++g) {
        float hg = s2[g];
        float4 wv = *(const float4*)(w + (size_t)g * DD);
        acc.x += hg * wv.x; acc.y += hg * wv.y; acc.z += hg * wv.z; acc.w += hg * wv.w;
    }
    float4 dc = *(const float4*)(decay + (size_t)i * DD + c0);
    float tl = t * (float)LL;
    acc.x *= expf(-fabsf(dc.x) * tl);
    acc.y *= expf(-fabsf(dc.y) * tl);
    acc.z *= expf(-fabsf(dc.z) * tl);
    acc.w *= expf(-fabsf(dc.w) * tl);
    *(float4*)(hout + ((size_t)i * TAPS + n) * DD + c0) = acc;
}

// ---------------------------------------------------------------------------
// Fused causal-conv (blocks 0..4095) + depthwise K=3 conv (blocks 4096..8191).
// Independent data paths; fused to cut dispatch count.
// ---------------------------------------------------------------------------
#define CTT 64
#define CCC 32
__global__ __launch_bounds__(256) void convdw_kernel(
    const float* __restrict__ v, const float* __restrict__ hflt, float* __restrict__ y,
    const unsigned short* __restrict__ ctrl, int ld,
    const float* __restrict__ cw, const float* __restrict__ cb,
    unsigned short* __restrict__ xc)
{
    const int bid = blockIdx.x;
    const int tid = threadIdx.x;

    if (bid >= 4096) {
        // depthwise conv
        size_t idx = (size_t)(bid - 4096) * 256 + tid;
        int c8 = (int)(idx & 127) * 8;
        size_t bt = idx >> 7;
        int t = (int)(bt & (LL - 1));

        const unsigned short* base = ctrl + bt * ld + c8;
        bf16x8 xm = {}, xp = {};
        bf16x8 x0 = *(const bf16x8*)(base);
        if (t > 0)      xm = *(const bf16x8*)(base - ld);
        if (t < LL - 1) xp = *(const bf16x8*)(base + ld);

        bf16x8 o;
        #pragma unroll
        for (int q = 0; q < 8; ++q) {
            int c = c8 + q;
            float r = cw[0 * DD + c] * bf2f((unsigned short)xm[q])
                    + cw[1 * DD + c] * bf2f((unsigned short)x0[q])
                    + cw[2 * DD + c] * bf2f((unsigned short)xp[q])
                    + cb[c];
            o[q] = (short)f2bf(r);
        }
        *(bf16x8*)(xc + bt * DD + c8) = o;
        return;
    }

    // causal 64-tap conv
    const int t0 = (bid & 63) * CTT;
    const int c0 = ((bid >> 6) & 31) * CCC;
    const int b  = bid >> 11;

    __shared__ float sv[128][CCC];
    __shared__ float sh[TAPS][CCC];

    const float* vb = v + (size_t)b * LL * DD;
    #pragma unroll
    for (int q = 0; q < 4; ++q) {
        int idx = tid + q * 256;
        int row = idx >> 3;
        int c4  = (idx & 7) * 4;
        int t = t0 - 64 + row;
        float4 val = make_float4(0.f, 0.f, 0.f, 0.f);
        if (t >= 0) val = *(const float4*)(vb + (size_t)t * DD + c0 + c4);
        *(float4*)(&sv[row][c4]) = val;
    }
    #pragma unroll
    for (int q = 0; q < 2; ++q) {
        int idx = tid + q * 256;
        int u   = idx >> 3;
        int c4  = (idx & 7) * 4;
        *(float4*)(&sh[u][c4]) = *(const float4*)(hflt + (size_t)u * DD + c0 + c4);
    }
    __syncthreads();

    const int tx = tid & 31;
    const int ty = tid >> 5;
    const int R0 = 64 + ty * 8;

    float acc[8] = {};
    #pragma unroll
    for (int m = 0; m < 8; ++m) {
        float W[15];
        #pragma unroll
        for (int p = 0; p < 15; ++p) W[p] = sv[R0 - 8 * m - 7 + p][tx];
        float h8[8];
        #pragma unroll
        for (int du = 0; du < 8; ++du) h8[du] = sh[8 * m + du][tx];
        #pragma unroll
        for (int du = 0; du < 8; ++du)
            #pragma unroll
            for (int j = 0; j < 8; ++j)
                acc[j] += h8[du] * W[7 + j - du];
    }

    float* yb = y + ((size_t)b * LL + t0) * DD + c0;
    #pragma unroll
    for (int j = 0; j < 8; ++j) yb[(size_t)(ty * 8 + j) * DD + tx] = acc[j];
}

// ---------------------------------------------------------------------------
// Phase-split tri-buffer bf16 MFMA GEMM (T3+T4+T5): C = A(Mx1024)@BT(Nx1024)^T + b
// BM=256, BN=128, BK=64, 512 thr (8 waves, 4M x 2N, per-wave 64x64).
// 3 LDS buffers (48KB each): read buf[t%3], tile t+1 landing in buf[(t+1)%3],
// stage tile t+2 into buf[(t+2)%3] -> no WAR hazard by construction.
// Per tile: 2 phases {8 ds_read + stage-issue -> barrier -> setprio 16 MFMA},
// then counted vmcnt(6) (t+2's 6 loads stay in flight) + barrier.
// EPI 0: f32  2: f32 gate-epi  3: bf16 gate-epi  4: split V f32/ctrl bf16
// ---------------------------------------------------------------------------
template <int EPI>
__global__ __launch_bounds__(512, 1) void gemm8p_kernel(
    const unsigned short* __restrict__ A,    // M x 1024
    const unsigned short* __restrict__ BT,   // N x 1024
    const float* __restrict__ bias,          // N
    const float* __restrict__ vconv,         // M x 1024 f32 (EPI 2/3)
    void* __restrict__ Cout,
    int Nblk,
    void* __restrict__ Cout2)
{
    constexpr int BUFB = 49152;              // A 32KB (4 chunks) + B 16KB (2 chunks)
    __shared__ char lds[3 * BUFB];

    const int tid  = threadIdx.x;
    const int wave = tid >> 6;
    const int lane = tid & 63;

    // bijective XCD swizzle (grid % 8 == 0: 768 or 256)
    const int nwg  = gridDim.x;
    const int orig = blockIdx.x;
    const int wg   = (orig & 7) * (nwg >> 3) + (orig >> 3);
    const int by   = wg / Nblk;
    const int bx   = wg % Nblk;

    const int wm  = (wave >> 1) * 64;        // 4 waves along M
    const int wn  = (wave & 1) * 64;         // 2 waves along N
    const int llo = lane & 15;
    const int lhi = lane >> 4;

    // ---- staging (pre-swizzled slot within each 64B chunk-row) ----
    const int srow = tid >> 2;               // 0..127 (chunk row)
    const int ssl  = tid & 3;
    const int ssrc = ssl ^ ((srow >> 1) & 3);
    const unsigned short* Asrc = A  + (size_t)(by * 256 + srow) * 1024 + ssrc * 8;
    const unsigned short* Bsrc = BT + (size_t)(bx * 128 + srow) * 1024 + ssrc * 8;
    char* ldsp = (char*)lds;
    const int wofs = wave * 1024;            // wave-uniform dest base within chunk

    // ---- ds_read offsets (kk=0; kk=1 adds 8192) ----
    // A chunk(rh,kk) at (rh*2+kk)*8192; B chunk(kk) at 32768 + kk*8192
    const int slot = lhi ^ ((llo >> 1) & 3);
    int offA[4], offB[4];
    #pragma unroll
    for (int mi = 0; mi < 4; ++mi) {
        int rowA = wm + mi * 16 + llo;       // 0..255
        offA[mi] = (rowA >> 7) * 16384 + (rowA & 127) * 64 + slot * 16;
    }
    #pragma unroll
    for (int ni = 0; ni < 4; ++ni) {
        int rowB = wn + ni * 16 + llo;       // 0..127
        offB[ni] = 32768 + rowB * 64 + slot * 16;
    }

    f32x4 acc[4][4] = {};

    // prologue: tile 0 -> buf0, tile 1 -> buf1 (12 loads); wait for tile 0 (6 oldest)
    {
        gl_lds16(Asrc,                        ldsp + 0 + wofs);
        gl_lds16(Asrc + 32,                   ldsp + 8192 + wofs);
        gl_lds16(Asrc + (size_t)128 * 1024,       ldsp + 16384 + wofs);
        gl_lds16(Asrc + (size_t)128 * 1024 + 32,  ldsp + 24576 + wofs);
        gl_lds16(Bsrc,                        ldsp + 32768 + wofs);
        gl_lds16(Bsrc + 32,                   ldsp + 40960 + wofs);
        gl_lds16(Asrc + 64,                   ldsp + BUFB + 0 + wofs);
        gl_lds16(Asrc + 96,                   ldsp + BUFB + 8192 + wofs);
        gl_lds16(Asrc + (size_t)128 * 1024 + 64,  ldsp + BUFB + 16384 + wofs);
        gl_lds16(Asrc + (size_t)128 * 1024 + 96,  ldsp + BUFB + 24576 + wofs);
        gl_lds16(Bsrc + 64,                   ldsp + BUFB + 32768 + wofs);
        gl_lds16(Bsrc + 96,                   ldsp + BUFB + 40960 + wofs);
    }
    asm volatile("s_waitcnt vmcnt(6)" ::: "memory");
    __builtin_amdgcn_sched_barrier(0);
    __builtin_amdgcn_s_barrier();
    __builtin_amdgcn_sched_barrier(0);

    int bcur = 0;
    for (int t = 0; t < 16; ++t) {
        const int bo  = bcur * BUFB;
        const int nb  = (bcur + 2 >= 3) ? bcur - 1 : bcur + 2;
        const int bo2 = nb * BUFB;
        const int k2  = (t + 2) * 64;
        const bool st = (t < 14);

        // ---- phase 0: kk = 0 ----
        bf16x8 a0 = *(const bf16x8*)(ldsp + bo + offA[0]);
        bf16x8 a1 = *(const bf16x8*)(ldsp + bo + offA[1]);
        bf16x8 a2 = *(const bf16x8*)(ldsp + bo + offA[2]);
        bf16x8 a3 = *(const bf16x8*)(ldsp + bo + offA[3]);
        bf16x8 b0 = *(const bf16x8*)(ldsp + bo + offB[0]);
        bf16x8 b1 = *(const bf16x8*)(ldsp + bo + offB[1]);
        bf16x8 b2 = *(const bf16x8*)(ldsp + bo + offB[2]);
        bf16x8 b3 = *(const bf16x8*)(ldsp + bo + offB[3]);
        if (st) {   // stage t+2: A rows 0-127
            gl_lds16(Asrc + k2,      ldsp + bo2 + 0 + wofs);
            gl_lds16(Asrc + 32 + k2, ldsp + bo2 + 8192 + wofs);
        }
        __builtin_amdgcn_s_barrier();
        __builtin_amdgcn_s_setprio(1);
        acc[0][0] = __builtin_amdgcn_mfma_f32_16x16x32_bf16(a0, b0, acc[0][0], 0, 0, 0);
        acc[0][1] = __builtin_amdgcn_mfma_f32_16x16x32_bf16(a0, b1, acc[0][1], 0, 0, 0);
        acc[0][2] = __builtin_amdgcn_mfma_f32_16x16x32_bf16(a0, b2, acc[0][2], 0, 0, 0);
        acc[0][3] = __builtin_amdgcn_mfma_f32_16x16x32_bf16(a0, b3, acc[0][3], 0, 0, 0);
        acc[1][0] = __builtin_amdgcn_mfma_f32_16x16x32_bf16(a1, b0, acc[1][0], 0, 0, 0);
        acc[1][1] = __builtin_amdgcn_mfma_f32_16x16x32_bf16(a1, b1, acc[1][1], 0, 0, 0);
        acc[1][2] = __builtin_amdgcn_mfma_f32_16x16x32_bf16(a1, b2, acc[1][2], 0, 0, 0);
        acc[1][3] = __builtin_amdgcn_mfma_f32_16x16x32_bf16(a1, b3, acc[1][3], 0, 0, 0);
        acc[2][0] = __builtin_amdgcn_mfma_f32_16x16x32_bf16(a2, b0, acc[2][0], 0, 0, 0);
        acc[2][1] = __builtin_amdgcn_mfma_f32_16x16x32_bf16(a2, b1, acc[2][1], 0, 0, 0);
        acc[2][2] = __builtin_amdgcn_mfma_f32_16x16x32_bf16(a2, b2, acc[2][2], 0, 0, 0);
        acc[2][3] = __builtin_amdgcn_mfma_f32_16x16x32_bf16(a2, b3, acc[2][3], 0, 0, 0);
        acc[3][0] = __builtin_amdgcn_mfma_f32_16x16x32_bf16(a3, b0, acc[3][0], 0, 0, 0);
        acc[3][1] = __builtin_amdgcn_mfma_f32_16x16x32_bf16(a3, b1, acc[3][1], 0, 0, 0);
        acc[3][2] = __builtin_amdgcn_mfma_f32_16x16x32_bf16(a3, b2, acc[3][2], 0, 0, 0);
        acc[3][3] = __builtin_amdgcn_mfma_f32_16x16x32_bf16(a3, b3, acc[3][3], 0, 0, 0);
        __builtin_amdgcn_s_setprio(0);

        // ---- phase 1: kk = 1 ----
        a0 = *(const bf16x8*)(ldsp + bo + offA[0] + 8192);
        a1 = *(const bf16x8*)(ldsp + bo + offA[1] + 8192);
        a2 = *(const bf16x8*)(ldsp + bo + offA[2] + 8192);
        a3 = *(const bf16x8*)(ldsp + bo + offA[3] + 8192);
        b0 = *(const bf16x8*)(ldsp + bo + offB[0] + 8192);
        b1 = *(const bf16x8*)(ldsp + bo + offB[1] + 8192);
        b2 = *(const bf16x8*)(ldsp + bo + offB[2] + 8192);
        b3 = *(const bf16x8*)(ldsp + bo + offB[3] + 8192);
        if (st) {   // stage t+2: A rows 128-255 + B
            gl_lds16(Asrc + (size_t)128 * 1024 + k2,      ldsp + bo2 + 16384 + wofs);
            gl_lds16(Asrc + (size_t)128 * 1024 + 32 + k2, ldsp + bo2 + 24576 + wofs);
            gl_lds16(Bsrc + k2,      ldsp + bo2 + 32768 + wofs);
            gl_lds16(Bsrc + 32 + k2, ldsp + bo2 + 40960 + wofs);
        }
        __builtin_amdgcn_s_barrier();
        __builtin_amdgcn_s_setprio(1);
        acc[0][0] = __builtin_amdgcn_mfma_f32_16x16x32_bf16(a0, b0, acc[0][0], 0, 0, 0);
        acc[0][1] = __builtin_amdgcn_mfma_f32_16x16x32_bf16(a0, b1, acc[0][1], 0, 0, 0);
        acc[0][2] = __builtin_amdgcn_mfma_f32_16x16x32_bf16(a0, b2, acc[0][2], 0, 0, 0);
        acc[0][3] = __builtin_amdgcn_mfma_f32_16x16x32_bf16(a0, b3, acc[0][3], 0, 0, 0);
        acc[1][0] = __builtin_amdgcn_mfma_f32_16x16x32_bf16(a1, b0, acc[1][0], 0, 0, 0);
        acc[1][1] = __builtin_amdgcn_mfma_f32_16x16x32_bf16(a1, b1, acc[1][1], 0, 0, 0);
        acc[1][2] = __builtin_amdgcn_mfma_f32_16x16x32_bf16(a1, b2, acc[1][2], 0, 0, 0);
        acc[1][3] = __builtin_amdgcn_mfma_f32_16x16x32_bf16(a1, b3, acc[1][3], 0, 0, 0);
        acc[2][0] = __builtin_amdgcn_mfma_f32_16x16x32_bf16(a2, b0, acc[2][0], 0, 0, 0);
        acc[2][1] = __builtin_amdgcn_mfma_f32_16x16x32_bf16(a2, b1, acc[2][1], 0, 0, 0);
        acc[2][2] = __builtin_amdgcn_mfma_f32_16x16x32_bf16(a2, b2, acc[2][2], 0, 0, 0);
        acc[2][3] = __builtin_amdgcn_mfma_f32_16x16x32_bf16(a2, b3, acc[2][3], 0, 0, 0);
        acc[3][0] = __builtin_amdgcn_mfma_f32_16x16x32_bf16(a3, b0, acc[3][0], 0, 0, 0);
        acc[3][1] = __builtin_amdgcn_mfma_f32_16x16x32_bf16(a3, b1, acc[3][1], 0, 0, 0);
        acc[3][2] = __builtin_amdgcn_mfma_f32_16x16x32_bf16(a3, b2, acc[3][2], 0, 0, 0);
        acc[3][3] = __builtin_amdgcn_mfma_f32_16x16x32_bf16(a3, b3, acc[3][3], 0, 0, 0);
        __builtin_amdgcn_s_setprio(0);

        // ---- tile end: ensure tile t+1 landed (everyone), keep t+2 in flight ----
        if (st)           asm volatile("s_waitcnt vmcnt(6)" ::: "memory");
        else if (t == 14) asm volatile("s_waitcnt vmcnt(0)" ::: "memory");
        if (t < 15) {
            __builtin_amdgcn_s_barrier();
            __builtin_amdgcn_sched_barrier(0);
        }
        bcur = (bcur + 1 >= 3) ? 0 : bcur + 1;
    }

    // ---- epilogue: C/D layout col=lane&15, row=(lane>>4)*4+reg ----
    #pragma unroll
    for (int ni = 0; ni < 4; ++ni) {
        const int col = bx * 128 + wn + ni * 16 + llo;
        const float bj = bias[col];
        #pragma unroll
        for (int mi = 0; mi < 4; ++mi) {
            #pragma unroll
            for (int r = 0; r < 4; ++r) {
                const int rowg = by * 256 + wm + mi * 16 + lhi * 4 + r;
                float v = acc[mi][ni][r] + bj;
                if (EPI == 0) {
                    ((float*)Cout)[(size_t)rowg * 1024 + col] = v;
                } else if (EPI == 4) {
                    if (col < 1024) ((float*)Cout)[(size_t)rowg * 1024 + col] = v;
                    else ((unsigned short*)Cout2)[(size_t)rowg * 2048 + (col - 1024)] = f2bf(v);
                } else {
                    float xc = bf2f(A[(size_t)rowg * 1024 + col]);
                    float vc = vconv[(size_t)rowg * 1024 + col];
                    float o  = vc * xc * (1.0f / (1.0f + expf(-v)));
                    if (EPI == 2) ((float*)Cout)[(size_t)rowg * 1024 + col] = o;
                    else          ((unsigned short*)Cout)[(size_t)rowg * 1024 + col] = f2bf(o);
                }
            }
        }
    }
}

// ---------------------------------------------------------------------------
extern "C" void kernel_launch(void* const* d_in, const int* in_sizes, int n_in,
                              void* d_out, int out_size, void* d_ws, size_t ws_size,
                              hipStream_t stream) {
    const float* x     = (const float*)d_in[0];
    const float* ipw   = (const float*)d_in[1];
    const float* ipb   = (const float*)d_in[2];
    const float* opw   = (const float*)d_in[3];
    const float* opb   = (const float*)d_in[4];
    const float* freqs = (const float*)d_in[5];
    const float* w1    = (const float*)d_in[6];
    const float* b1    = (const float*)d_in[7];
    const float* w2    = (const float*)d_in[8];
    const float* b2    = (const float*)d_in[9];
    const float* w3    = (const float*)d_in[10];
    const float* b3    = (const float*)d_in[11];
    const float* decay = (const float*)d_in[12];
    const float* cw    = (const float*)d_in[13];
    const float* cb    = (const float*)d_in[14];
    const float* gw    = (const float*)d_in[15];
    const float* gb    = (const float*)d_in[16];
    float* out = (float*)d_out;

    // workspace layout
    char* w = (char*)d_ws;
    float* h             = (float*)w;                                // NORD*TAPS*DD f32
    unsigned short* ipwT = (unsigned short*)(w + (size_t)1048576);   // 3072x1024 bf16
    unsigned short* gw0T = ipwT + (size_t)3072 * 1024;               // 1024x1024
    unsigned short* gw1T = gw0T + (size_t)1024 * 1024;
    unsigned short* opwT = gw1T + (size_t)1024 * 1024;
    unsigned short* xb   = opwT + (size_t)1024 * 1024;               // 8192x1024 bf16 (x, later v2)
    float* V             = (float*)(xb + (size_t)8192 * 1024);       // 8192x1024 f32 (v0, v1)
    unsigned short* ctrlB= (unsigned short*)(V + (size_t)8192 * 1024); // 8192x2048 bf16
    unsigned short* xcB  = ctrlB + (size_t)8192 * 2048;              // 8192x1024 bf16
    float* vconv         = out;                                      // d_out as f32 scratch

    dim3 blk(256);
    dim3 blk512(512);

    // prep: cvt + 4 weight transposes + implicit filters (one dispatch)
    prep_kernel<<<10368, blk, 0, stream>>>(x, xb, ipw, ipwT, gw, gw0T, gw1T,
                                           opw, opwT, freqs, w1, b1, w2, b2, w3, b3, decay, h);

    // fused in_proj: cols<1024 -> V (f32), cols>=1024 -> ctrlB (bf16)
    gemm8p_kernel<4><<<768, blk512, 0, stream>>>(xb, ipwT, ipb, nullptr, V, 24, ctrlB);

    // order 0: conv(V)->vconv  ||  dwconv(ctrl0)->xcB, then gate GEMM
    convdw_kernel<<<8192, blk, 0, stream>>>(V, h, vconv, ctrlB, 2048, cw, cb, xcB);
    gemm8p_kernel<2><<<256, blk512, 0, stream>>>(xcB, gw0T, gb, vconv, V, 8, nullptr);

    // order 1
    convdw_kernel<<<8192, blk, 0, stream>>>(V, h + (size_t)TAPS * DD, vconv,
                                            ctrlB + 1024, 2048, cw + (size_t)KW * DD, cb + DD, xcB);
    gemm8p_kernel<3><<<256, blk512, 0, stream>>>(xcB, gw1T, gb + DD, vconv, xb, 8, nullptr);

    // out = v2 @ opw + opb
    gemm8p_kernel<0><<<256, blk512, 0, stream>>>(xb, opwT, opb, nullptr, out, 8, nullptr);
}